// Round 1
// baseline (166.770 us; speedup 1.0000x reference)
//
#include <hip/hip_runtime.h>
#include <math.h>

#define NB 2
#define NN 512
#define NH 8
#define ND 64

// ---------------- LDS 16B-quad XOR swizzle helpers (row-major [rows][64]) ----
__device__ __forceinline__ float4 ld4(const float* s, int row, int c4) {
  return ((const float4*)s)[row * 16 + (c4 ^ (row & 7))];
}
__device__ __forceinline__ void st4(float* s, int row, int c4, float4 val) {
  ((float4*)s)[row * 16 + (c4 ^ (row & 7))] = val;
}
__device__ __forceinline__ void st1(float* s, int row, int col, float val) {
  s[row * 64 + ((((col >> 2) ^ (row & 7)) << 2) | (col & 3))] = val;
}

// ---------------- K1: QKV GEMM  C[1024,1536] = x[1024,512] @ Wqkv ------------
// scatter into q,k,v laid out [B,H,N,D]
__global__ __launch_bounds__(256) void k_qkv(const float* __restrict__ x,
                                             const float* __restrict__ W,
                                             float* __restrict__ qg,
                                             float* __restrict__ kg,
                                             float* __restrict__ vg) {
  __shared__ __align__(16) float As[32][68];
  __shared__ __align__(16) float Bs[32][64];
  const int bid = blockIdx.x;          // 16 * 24
  const int mt = bid / 24, nt = bid % 24;
  const int m0 = mt * 64, n0 = nt * 64;
  const int t = threadIdx.x;
  const int tm = t >> 4, tn = t & 15;
  float acc[4][4] = {};
  for (int k0 = 0; k0 < 512; k0 += 32) {
    #pragma unroll
    for (int c = 0; c < 2; ++c) {
      int idx = t + c * 256;           // 0..511
      int m = idx >> 3, k4 = idx & 7;  // 64 rows x 8 quads
      const float4 a = *(const float4*)&x[(m0 + m) * 512 + k0 + k4 * 4];
      As[k4 * 4 + 0][m] = a.x; As[k4 * 4 + 1][m] = a.y;
      As[k4 * 4 + 2][m] = a.z; As[k4 * 4 + 3][m] = a.w;
    }
    #pragma unroll
    for (int c = 0; c < 2; ++c) {
      int idx = t + c * 256;
      int kk = idx >> 4, n4 = idx & 15;
      *(float4*)&Bs[kk][n4 * 4] = *(const float4*)&W[(k0 + kk) * 1536 + n0 + n4 * 4];
    }
    __syncthreads();
    #pragma unroll
    for (int kk = 0; kk < 32; ++kk) {
      const float4 a4 = *(const float4*)&As[kk][tm * 4];
      const float4 b4 = *(const float4*)&Bs[kk][tn * 4];
      float ra[4] = {a4.x, a4.y, a4.z, a4.w};
      float rb[4] = {b4.x, b4.y, b4.z, b4.w};
      #pragma unroll
      for (int ii = 0; ii < 4; ++ii)
        #pragma unroll
        for (int jj = 0; jj < 4; ++jj)
          acc[ii][jj] = fmaf(ra[ii], rb[jj], acc[ii][jj]);
    }
    __syncthreads();
  }
  // epilogue: tile covers exactly one section & head (n0 multiple of 64)
  const int sec = n0 >> 9;
  const int hh = (n0 >> 6) & 7;
  float* dst = (sec == 0) ? qg : (sec == 1) ? kg : vg;
  #pragma unroll
  for (int ii = 0; ii < 4; ++ii) {
    int row = m0 + tm * 4 + ii;
    int b = row >> 9, n = row & 511;
    float4 o4 = make_float4(acc[ii][0], acc[ii][1], acc[ii][2], acc[ii][3]);
    *(float4*)&dst[((b * 8 + hh) * 512 + n) * 64 + tn * 4] = o4;
  }
}

// ---------------- K2: RPE bias MLP  -> bias[B,H,N,N] ------------------------
__global__ __launch_bounds__(256) void k_bias(const float* __restrict__ pos,
                                              const float* __restrict__ W1,
                                              const float* __restrict__ b1,
                                              const float* __restrict__ W2,
                                              const float* __restrict__ b2,
                                              float* __restrict__ bias) {
  const int t = threadIdx.x;
  const int gid = blockIdx.x * 256 + t;   // < 524288
  const int b = gid >> 18;
  const int i = (gid >> 9) & 511;
  const int j = gid & 511;
  const float pix = pos[(b * 512 + i) * 2 + 0];
  const float piy = pos[(b * 512 + i) * 2 + 1];
  const float pjx = pos[(b * 512 + j) * 2 + 0];
  const float pjy = pos[(b * 512 + j) * 2 + 1];
  float ux = (pjx - pix) * 0.1f; ux = ux / (1.0f + fabsf(ux));
  float uy = (pjy - piy) * 0.1f; uy = uy / (1.0f + fabsf(uy));

  float h[16];
  #pragma unroll
  for (int r = 0; r < 16; ++r)
    h[r] = b1[r] + ux * W1[r] + uy * W1[65 * 16 + r];

  const float PIf = 3.14159265358979323846f;
  float sx, cx, sy, cy;
  sincosf(ux * PIf, &sx, &cx);
  sincosf(uy * PIf, &sy, &cy);
  float sxk = sx, cxk = cx, syk = sy, cyk = cy;
  for (int f = 0; f < 32; ++f) {
    const float* wsx = &W1[(1 + f) * 16];
    const float* wcx = &W1[(33 + f) * 16];
    const float* wsy = &W1[(66 + f) * 16];
    const float* wcy = &W1[(98 + f) * 16];
    #pragma unroll
    for (int r = 0; r < 16; ++r)
      h[r] += sxk * wsx[r] + cxk * wcx[r] + syk * wsy[r] + cyk * wcy[r];
    float nsx = sxk * cx + cxk * sx; cxk = cxk * cx - sxk * sx; sxk = nsx;
    float nsy = syk * cy + cyk * sy; cyk = cyk * cy - syk * sy; syk = nsy;
  }
  // exact gelu
  #pragma unroll
  for (int r = 0; r < 16; ++r)
    h[r] = 0.5f * h[r] * (1.0f + erff(h[r] * 0.70710678118654752f));
  float o[8];
  #pragma unroll
  for (int c = 0; c < 8; ++c) o[c] = b2[c];
  #pragma unroll
  for (int r = 0; r < 16; ++r)
    #pragma unroll
    for (int c = 0; c < 8; ++c)
      o[c] = fmaf(h[r], W2[r * 8 + c], o[c]);
  // bias[b][h][i][j]  (coalesced: j = lane-consecutive)
  const int base = b * 2097152 + i * 512 + j;
  #pragma unroll
  for (int c = 0; c < 8; ++c)
    bias[base + c * 262144] = o[c];
}

// ---------------- K3: fused attention (flash-style, fp32) -------------------
// block: (b, h, 32-row q tile); 256 thr; thread: rows {tm, tm+16}, cols {tn+16jj}
__global__ __launch_bounds__(256) void k_attn(const float* __restrict__ qg,
                                              const float* __restrict__ kg,
                                              const float* __restrict__ vg,
                                              const float* __restrict__ bias,
                                              float* __restrict__ ao) {
  __shared__ __align__(16) float qs[32 * 64];
  __shared__ __align__(16) float ks[64 * 64];
  __shared__ __align__(16) float vt[64 * 64];   // vt[d][j]
  __shared__ __align__(16) float ps[32 * 64];

  const int bid = blockIdx.x;           // 256
  const int it = bid & 15;
  const int h = (bid >> 4) & 7;
  const int b = bid >> 7;
  const int i0 = it * 32;
  const int t = threadIdx.x;
  const int tm = t >> 4, tn = t & 15;

  const float* qp = qg + ((b * 8 + h) * 512 + i0) * 64;
  const float* kp = kg + ((b * 8 + h) * 512) * 64;
  const float* vp = vg + ((b * 8 + h) * 512) * 64;
  const float* bp = bias + ((b * 8 + h) * 512 + i0) * 512;

  // stage q (pre-scaled by 1/8)
  #pragma unroll
  for (int c = 0; c < 2; ++c) {
    int idx = t + c * 256;
    int r = idx >> 4, c4 = idx & 15;
    float4 a = *(const float4*)&qp[r * 64 + c4 * 4];
    a.x *= 0.125f; a.y *= 0.125f; a.z *= 0.125f; a.w *= 0.125f;
    st4(qs, r, c4, a);
  }

  float mrun[2] = {-1e30f, -1e30f};
  float lrun[2] = {0.f, 0.f};
  float o[2][4] = {};

  for (int jt = 0; jt < 8; ++jt) {
    const int j0 = jt * 64;
    __syncthreads();   // protect ks/vt/ps from previous iteration (and qs staging, iter 0)
    #pragma unroll
    for (int c = 0; c < 4; ++c) {
      int idx = t + c * 256;
      int r = idx >> 4, c4 = idx & 15;
      float4 kv = *(const float4*)&kp[(j0 + r) * 64 + c4 * 4];
      st4(ks, r, c4, kv);
      float4 vv = *(const float4*)&vp[(j0 + r) * 64 + c4 * 4];
      st1(vt, c4 * 4 + 0, r, vv.x);
      st1(vt, c4 * 4 + 1, r, vv.y);
      st1(vt, c4 * 4 + 2, r, vv.z);
      st1(vt, c4 * 4 + 3, r, vv.w);
    }
    __syncthreads();
    // scores (init with RPE bias)
    float s[2][4];
    #pragma unroll
    for (int ii = 0; ii < 2; ++ii)
      #pragma unroll
      for (int jj = 0; jj < 4; ++jj)
        s[ii][jj] = bp[(ii * 16 + tm) * 512 + j0 + jj * 16 + tn];
    #pragma unroll
    for (int c4 = 0; c4 < 16; ++c4) {
      float4 a0 = ld4(qs, tm, c4);
      float4 a1 = ld4(qs, tm + 16, c4);
      #pragma unroll
      for (int jj = 0; jj < 4; ++jj) {
        float4 b4 = ld4(ks, jj * 16 + tn, c4);
        s[0][jj] += a0.x * b4.x + a0.y * b4.y + a0.z * b4.z + a0.w * b4.w;
        s[1][jj] += a1.x * b4.x + a1.y * b4.y + a1.z * b4.z + a1.w * b4.w;
      }
    }
    // online softmax; rows live across the 16 lanes sharing tm
    #pragma unroll
    for (int ii = 0; ii < 2; ++ii) {
      float mx = fmaxf(fmaxf(s[ii][0], s[ii][1]), fmaxf(s[ii][2], s[ii][3]));
      #pragma unroll
      for (int off = 8; off >= 1; off >>= 1)
        mx = fmaxf(mx, __shfl_xor(mx, off, 64));
      float mnew = fmaxf(mrun[ii], mx);
      float sc = __expf(mrun[ii] - mnew);
      mrun[ii] = mnew;
      float psum = 0.f;
      #pragma unroll
      for (int jj = 0; jj < 4; ++jj) {
        float p = __expf(s[ii][jj] - mnew);
        psum += p;
        st1(ps, ii * 16 + tm, jj * 16 + tn, p);
      }
      #pragma unroll
      for (int off = 8; off >= 1; off >>= 1)
        psum += __shfl_xor(psum, off, 64);
      lrun[ii] = lrun[ii] * sc + psum;
      #pragma unroll
      for (int jj = 0; jj < 4; ++jj) o[ii][jj] *= sc;
    }
    __syncthreads();
    // PV: o[ii][jj], row = ii*16+tm, d = jj*16+tn
    #pragma unroll
    for (int j4 = 0; j4 < 16; ++j4) {
      float4 p0 = ld4(ps, tm, j4);
      float4 p1 = ld4(ps, tm + 16, j4);
      #pragma unroll
      for (int jj = 0; jj < 4; ++jj) {
        float4 vv = ld4(vt, jj * 16 + tn, j4);
        o[0][jj] += p0.x * vv.x + p0.y * vv.y + p0.z * vv.z + p0.w * vv.w;
        o[1][jj] += p1.x * vv.x + p1.y * vv.y + p1.z * vv.z + p1.w * vv.w;
      }
    }
  }
  // epilogue: ao[b, i, h*64 + d]
  float* aop = ao + (b * 512 + i0) * 512 + h * 64;
  #pragma unroll
  for (int ii = 0; ii < 2; ++ii) {
    float inv = 1.0f / lrun[ii];
    int row = ii * 16 + tm;
    #pragma unroll
    for (int jj = 0; jj < 4; ++jj)
      aop[row * 512 + jj * 16 + tn] = o[ii][jj] * inv;
  }
}

// ---------------- K4: output GEMM  out = ao[1024,512] @ Wout + bout ---------
__global__ __launch_bounds__(256) void k_out(const float* __restrict__ A,
                                             const float* __restrict__ W,
                                             const float* __restrict__ bout,
                                             float* __restrict__ out) {
  __shared__ __align__(16) float As[32][68];
  __shared__ __align__(16) float Bs[32][64];
  const int bid = blockIdx.x;          // 16 * 8
  const int mt = bid >> 3, nt = bid & 7;
  const int m0 = mt * 64, n0 = nt * 64;
  const int t = threadIdx.x;
  const int tm = t >> 4, tn = t & 15;
  float acc[4][4] = {};
  for (int k0 = 0; k0 < 512; k0 += 32) {
    #pragma unroll
    for (int c = 0; c < 2; ++c) {
      int idx = t + c * 256;
      int m = idx >> 3, k4 = idx & 7;
      const float4 a = *(const float4*)&A[(m0 + m) * 512 + k0 + k4 * 4];
      As[k4 * 4 + 0][m] = a.x; As[k4 * 4 + 1][m] = a.y;
      As[k4 * 4 + 2][m] = a.z; As[k4 * 4 + 3][m] = a.w;
    }
    #pragma unroll
    for (int c = 0; c < 2; ++c) {
      int idx = t + c * 256;
      int kk = idx >> 4, n4 = idx & 15;
      *(float4*)&Bs[kk][n4 * 4] = *(const float4*)&W[(k0 + kk) * 512 + n0 + n4 * 4];
    }
    __syncthreads();
    #pragma unroll
    for (int kk = 0; kk < 32; ++kk) {
      const float4 a4 = *(const float4*)&As[kk][tm * 4];
      const float4 b4 = *(const float4*)&Bs[kk][tn * 4];
      float ra[4] = {a4.x, a4.y, a4.z, a4.w};
      float rb[4] = {b4.x, b4.y, b4.z, b4.w};
      #pragma unroll
      for (int ii = 0; ii < 4; ++ii)
        #pragma unroll
        for (int jj = 0; jj < 4; ++jj)
          acc[ii][jj] = fmaf(ra[ii], rb[jj], acc[ii][jj]);
    }
    __syncthreads();
  }
  const float4 bb = *(const float4*)&bout[n0 + tn * 4];
  #pragma unroll
  for (int ii = 0; ii < 4; ++ii) {
    int row = m0 + tm * 4 + ii;
    float4 o4 = make_float4(acc[ii][0] + bb.x, acc[ii][1] + bb.y,
                            acc[ii][2] + bb.z, acc[ii][3] + bb.w);
    *(float4*)&out[row * 512 + n0 + tn * 4] = o4;
  }
}

extern "C" void kernel_launch(void* const* d_in, const int* in_sizes, int n_in,
                              void* d_out, int out_size, void* d_ws, size_t ws_size,
                              hipStream_t stream) {
  const float* x    = (const float*)d_in[0];
  const float* pos  = (const float*)d_in[1];
  const float* Wqkv = (const float*)d_in[2];
  const float* Wout = (const float*)d_in[3];
  const float* bout = (const float*)d_in[4];
  const float* W1   = (const float*)d_in[5];
  const float* b1   = (const float*)d_in[6];
  const float* W2   = (const float*)d_in[7];
  const float* b2   = (const float*)d_in[8];
  float* out = (float*)d_out;
  float* ws = (float*)d_ws;

  float* q    = ws;               // 524288
  float* k    = ws + 524288;      // 524288
  float* v    = ws + 1048576;     // 524288
  float* bias = ws + 1572864;     // 4194304  [B,H,N,N]
  float* ao   = ws + 5767168;     // 524288   [B,N,512]

  hipLaunchKernelGGL(k_qkv,  dim3(384),  dim3(256), 0, stream, x, Wqkv, q, k, v);
  hipLaunchKernelGGL(k_bias, dim3(2048), dim3(256), 0, stream, pos, W1, b1, W2, b2, bias);
  hipLaunchKernelGGL(k_attn, dim3(256),  dim3(256), 0, stream, q, k, v, bias, ao);
  hipLaunchKernelGGL(k_out,  dim3(128),  dim3(256), 0, stream, ao, Wout, bout, out);
}

// Round 2
// 101.320 us; speedup vs baseline: 1.6460x; 1.6460x over previous
//
#include <hip/hip_runtime.h>
#include <hip/hip_fp16.h>
#include <math.h>

typedef __attribute__((ext_vector_type(8))) short bf16x8;
typedef __attribute__((ext_vector_type(4))) float f32x4;

#define TBL 8192
#define UMAXV (1.0f/11.0f)

__device__ __forceinline__ unsigned short f2bf(float f) {
  unsigned u = __builtin_bit_cast(unsigned, f);
  u = (u + 0x7fffu + ((u >> 16) & 1u)) >> 16;
  return (unsigned short)u;
}
__device__ __forceinline__ float bf2f(unsigned short s) {
  unsigned u = ((unsigned)s) << 16;
  return __builtin_bit_cast(float, u);
}
__device__ __forceinline__ void split2(float f, unsigned short& hi, unsigned short& lo) {
  hi = f2bf(f);
  lo = f2bf(f - bf2f(hi));
}

// ---------------- K1: QKV GEMM  [1024,1536] = x[1024,512] @ Wqkv ------------
// emits: qhi/qlo, khi/klo  [B,H,N,64] bf16 (q pre-scaled 1/8)
//        vthi/vtlo         [B,H,64,N] bf16 (transposed via LDS)
__global__ __launch_bounds__(256) void k_qkv(const float* __restrict__ x,
                                             const float* __restrict__ W,
                                             unsigned short* __restrict__ qhi,
                                             unsigned short* __restrict__ qlo,
                                             unsigned short* __restrict__ khi,
                                             unsigned short* __restrict__ klo,
                                             unsigned short* __restrict__ vthi,
                                             unsigned short* __restrict__ vtlo) {
  __shared__ __align__(16) float smem[64 * 68];           // As(32x68) + Bs(32x64) / T(64x68)
  float (*As)[68] = (float(*)[68])smem;
  float (*Bs)[64] = (float(*)[64])(smem + 32 * 68);
  const int bid = blockIdx.x;          // 16 * 24
  const int mt = bid / 24, nt = bid % 24;
  const int m0 = mt * 64, n0 = nt * 64;
  const int t = threadIdx.x;
  const int tm = t >> 4, tn = t & 15;
  float acc[4][4] = {};
  for (int k0 = 0; k0 < 512; k0 += 32) {
    #pragma unroll
    for (int c = 0; c < 2; ++c) {
      int idx = t + c * 256;
      int m = idx >> 3, k4 = idx & 7;
      const float4 a = *(const float4*)&x[(m0 + m) * 512 + k0 + k4 * 4];
      As[k4 * 4 + 0][m] = a.x; As[k4 * 4 + 1][m] = a.y;
      As[k4 * 4 + 2][m] = a.z; As[k4 * 4 + 3][m] = a.w;
    }
    #pragma unroll
    for (int c = 0; c < 2; ++c) {
      int idx = t + c * 256;
      int kk = idx >> 4, n4 = idx & 15;
      *(float4*)&Bs[kk][n4 * 4] = *(const float4*)&W[(k0 + kk) * 1536 + n0 + n4 * 4];
    }
    __syncthreads();
    #pragma unroll
    for (int kk = 0; kk < 32; ++kk) {
      const float4 a4 = *(const float4*)&As[kk][tm * 4];
      const float4 b4 = *(const float4*)&Bs[kk][tn * 4];
      float ra[4] = {a4.x, a4.y, a4.z, a4.w};
      float rb[4] = {b4.x, b4.y, b4.z, b4.w};
      #pragma unroll
      for (int ii = 0; ii < 4; ++ii)
        #pragma unroll
        for (int jj = 0; jj < 4; ++jj)
          acc[ii][jj] = fmaf(ra[ii], rb[jj], acc[ii][jj]);
    }
    __syncthreads();
  }
  const int sec = n0 >> 9;
  const int hh = (n0 >> 6) & 7;
  if (sec < 2) {
    unsigned short* dh = (sec == 0) ? qhi : khi;
    unsigned short* dl = (sec == 0) ? qlo : klo;
    const float scl = (sec == 0) ? 0.125f : 1.0f;
    #pragma unroll
    for (int ii = 0; ii < 4; ++ii) {
      int row = m0 + tm * 4 + ii;
      int b = row >> 9, n = row & 511;
      ushort4 h4, l4;
      split2(acc[ii][0] * scl, h4.x, l4.x);
      split2(acc[ii][1] * scl, h4.y, l4.y);
      split2(acc[ii][2] * scl, h4.z, l4.z);
      split2(acc[ii][3] * scl, h4.w, l4.w);
      int addr = ((b * 8 + hh) * 512 + n) * 64 + tn * 4;
      *(ushort4*)&dh[addr] = h4;
      *(ushort4*)&dl[addr] = l4;
    }
  } else {
    // transpose v tile [64 n][64 d] -> vt[d][n] through LDS
    float* T = smem;
    #pragma unroll
    for (int ii = 0; ii < 4; ++ii)
      #pragma unroll
      for (int jj = 0; jj < 4; ++jj)
        T[(tn * 4 + jj) * 68 + tm * 4 + ii] = acc[ii][jj];
    __syncthreads();
    const int d = t >> 2, nq = (t & 3) * 16;
    const int b = m0 >> 9, nb = m0 & 511;
    #pragma unroll
    for (int c = 0; c < 4; ++c) {
      float4 vv = *(float4*)&T[d * 68 + nq + c * 4];
      ushort4 hv, lv;
      split2(vv.x, hv.x, lv.x);
      split2(vv.y, hv.y, lv.y);
      split2(vv.z, hv.z, lv.z);
      split2(vv.w, hv.w, lv.w);
      int addr = ((b * 8 + hh) * 64 + d) * 512 + nb + nq + c * 4;
      *(ushort4*)&vthi[addr] = hv;
      *(ushort4*)&vtlo[addr] = lv;
    }
  }
}

// ---------------- K2a: RPE hidden-layer tables ------------------------------
// Tx[e][r] = b1[r] + u*W1[0][r] + sum_k sin(k pi u) W1[k][r] + cos(k pi u) W1[32+k][r]
// Ty[e][r] =         u*W1[65][r] + sum_k sin W1[65+k][r] + cos W1[97+k][r]
__global__ __launch_bounds__(256) void k_tab(const float* __restrict__ W1,
                                             const float* __restrict__ b1,
                                             __half* __restrict__ Tx,
                                             __half* __restrict__ Ty) {
  int gid = blockIdx.x * 256 + threadIdx.x;   // TBL*32
  int e = gid >> 5, c = gid & 31;
  float u = -UMAXV + (2.0f * UMAXV) * (float)e / (float)(TBL - 1);
  const int xpart = (c < 16);
  const int col = c & 15;
  const int base = xpart ? 0 : 65;
  float sum = u * W1[base * 16 + col] + (xpart ? b1[col] : 0.0f);
  float s1, c1;
  sincosf(u * 3.14159265358979323846f, &s1, &c1);
  float sk = s1, ck = c1;
  for (int k = 1; k <= 32; ++k) {
    sum += sk * W1[(base + k) * 16 + col] + ck * W1[(base + 32 + k) * 16 + col];
    float ns = sk * c1 + ck * s1;
    ck = ck * c1 - sk * s1;
    sk = ns;
  }
  (xpart ? Tx : Ty)[e * 16 + col] = __float2half(sum);
}

// ---------------- K2b: RPE bias via table lookup -> bias bf16 [B,H,N,N] ------
__global__ __launch_bounds__(256) void k_bias(const float* __restrict__ pos,
                                              const __half* __restrict__ Tx,
                                              const __half* __restrict__ Ty,
                                              const float* __restrict__ W2,
                                              const float* __restrict__ b2,
                                              unsigned short* __restrict__ bias) {
  const int gid = blockIdx.x * 256 + threadIdx.x;   // < 524288
  const int b = gid >> 18;
  const int i = (gid >> 9) & 511;
  const int j = gid & 511;
  const float pix = pos[(b * 512 + i) * 2 + 0];
  const float piy = pos[(b * 512 + i) * 2 + 1];
  const float pjx = pos[(b * 512 + j) * 2 + 0];
  const float pjy = pos[(b * 512 + j) * 2 + 1];
  float txv = (pjx - pix) * 0.1f; float ux = txv / (1.0f + fabsf(txv));
  float tyv = (pjy - piy) * 0.1f; float uy = tyv / (1.0f + fabsf(tyv));
  const float invstep = (float)(TBL - 1) / (2.0f * UMAXV);
  float fx = (ux + UMAXV) * invstep;
  int ix = (int)fx; ix = min(max(ix, 0), TBL - 2);
  float wx = fx - (float)ix;
  float fy = (uy + UMAXV) * invstep;
  int iy = (int)fy; iy = min(max(iy, 0), TBL - 2);
  float wy = fy - (float)iy;

  __half hx0[16], hx1[16], hy0[16], hy1[16];
  *(uint4*)&hx0[0] = *(const uint4*)&Tx[ix * 16];
  *(uint4*)&hx0[8] = *(const uint4*)&Tx[ix * 16 + 8];
  *(uint4*)&hx1[0] = *(const uint4*)&Tx[(ix + 1) * 16];
  *(uint4*)&hx1[8] = *(const uint4*)&Tx[(ix + 1) * 16 + 8];
  *(uint4*)&hy0[0] = *(const uint4*)&Ty[iy * 16];
  *(uint4*)&hy0[8] = *(const uint4*)&Ty[iy * 16 + 8];
  *(uint4*)&hy1[0] = *(const uint4*)&Ty[(iy + 1) * 16];
  *(uint4*)&hy1[8] = *(const uint4*)&Ty[(iy + 1) * 16 + 8];

  float o[8];
  #pragma unroll
  for (int c = 0; c < 8; ++c) o[c] = b2[c];
  #pragma unroll
  for (int r = 0; r < 16; ++r) {
    float ax = __half2float(hx0[r]);
    float bx = __half2float(hx1[r]);
    float ay = __half2float(hy0[r]);
    float by = __half2float(hy1[r]);
    float hv = fmaf(wx, bx - ax, ax) + fmaf(wy, by - ay, ay);
    // exact-ish gelu: erf via A&S 7.1.26 (|err| < 1.5e-7)
    float z = hv * 0.70710678118654752f;
    float az = fabsf(z);
    float tt = __builtin_amdgcn_rcpf(fmaf(0.3275911f, az, 1.0f));
    float poly = ((((1.061405429f * tt - 1.453152027f) * tt + 1.421413741f) * tt
                   - 0.284496736f) * tt + 0.254829592f) * tt;
    float ex = __expf(-z * z);
    float erfv = copysignf(fmaf(-poly, ex, 1.0f), z);
    float g = 0.5f * hv * (1.0f + erfv);
    #pragma unroll
    for (int c = 0; c < 8; ++c)
      o[c] = fmaf(g, W2[r * 8 + c], o[c]);
  }
  #pragma unroll
  for (int c = 0; c < 8; ++c)
    bias[((b * 8 + c) * 512 + i) * 512 + j] = f2bf(o[c]);
}

// ---------------- K3: MFMA flash attention ----------------------------------
// grid 512 = (b, h, 16-row i-tile); 8 waves, wave w owns j in [w*64, w*64+64)
__global__ __launch_bounds__(512) void k_attn(
    const unsigned short* __restrict__ qhi, const unsigned short* __restrict__ qlo,
    const unsigned short* __restrict__ khi, const unsigned short* __restrict__ klo,
    const unsigned short* __restrict__ vthi, const unsigned short* __restrict__ vtlo,
    const unsigned short* __restrict__ bias, float* __restrict__ ao) {
  __shared__ __align__(16) unsigned short psu[8 * 512];   // per-wave P [16 q][32 j] bf16
  __shared__ __align__(16) float olds[8 * 16 * 65];       // padded partial O
  __shared__ float mls[8 * 16 * 2];

  const int bid = blockIdx.x;
  const int it = bid & 31, h = (bid >> 5) & 7, b = bid >> 8;
  const int i0 = it * 16;
  const int bh = b * 8 + h;
  const int tid = threadIdx.x;
  const int w = tid >> 6, lane = tid & 63;
  const int blk = lane >> 4, jc = lane & 15;

  // Q A-frags (row = lane&15, k = blk*8 + i), stay in regs
  const int qoff = (bh * 512 + i0 + jc) * 64 + blk * 8;
  const bf16x8 qa0h = *(const bf16x8*)&qhi[qoff];
  const bf16x8 qa1h = *(const bf16x8*)&qhi[qoff + 32];
  const bf16x8 qa0l = *(const bf16x8*)&qlo[qoff];
  const bf16x8 qa1l = *(const bf16x8*)&qlo[qoff + 32];

  float m[4] = {-1e30f, -1e30f, -1e30f, -1e30f};
  float l[4] = {0.f, 0.f, 0.f, 0.f};
  f32x4 o[4];
  #pragma unroll
  for (int dt = 0; dt < 4; ++dt) o[dt] = f32x4{0.f, 0.f, 0.f, 0.f};

  unsigned short* pw = &psu[w * 512];

  #pragma unroll
  for (int jt = 0; jt < 2; ++jt) {
    const int j0 = w * 64 + jt * 32;
    const int rA = (bh * 512 + j0 + jc) * 64 + blk * 8;
    const int rB = rA + 16 * 64;
    bf16x8 kA0h = *(const bf16x8*)&khi[rA];
    bf16x8 kA1h = *(const bf16x8*)&khi[rA + 32];
    bf16x8 kA0l = *(const bf16x8*)&klo[rA];
    bf16x8 kA1l = *(const bf16x8*)&klo[rA + 32];
    bf16x8 kB0h = *(const bf16x8*)&khi[rB];
    bf16x8 kB1h = *(const bf16x8*)&khi[rB + 32];
    bf16x8 kB0l = *(const bf16x8*)&klo[rB];
    bf16x8 kB1l = *(const bf16x8*)&klo[rB + 32];

    f32x4 aA = {0.f, 0.f, 0.f, 0.f};
    aA = __builtin_amdgcn_mfma_f32_16x16x32_bf16(qa0h, kA0h, aA, 0, 0, 0);
    aA = __builtin_amdgcn_mfma_f32_16x16x32_bf16(qa0h, kA0l, aA, 0, 0, 0);
    aA = __builtin_amdgcn_mfma_f32_16x16x32_bf16(qa0l, kA0h, aA, 0, 0, 0);
    aA = __builtin_amdgcn_mfma_f32_16x16x32_bf16(qa1h, kA1h, aA, 0, 0, 0);
    aA = __builtin_amdgcn_mfma_f32_16x16x32_bf16(qa1h, kA1l, aA, 0, 0, 0);
    aA = __builtin_amdgcn_mfma_f32_16x16x32_bf16(qa1l, kA1h, aA, 0, 0, 0);
    f32x4 aB = {0.f, 0.f, 0.f, 0.f};
    aB = __builtin_amdgcn_mfma_f32_16x16x32_bf16(qa0h, kB0h, aB, 0, 0, 0);
    aB = __builtin_amdgcn_mfma_f32_16x16x32_bf16(qa0h, kB0l, aB, 0, 0, 0);
    aB = __builtin_amdgcn_mfma_f32_16x16x32_bf16(qa0l, kB0h, aB, 0, 0, 0);
    aB = __builtin_amdgcn_mfma_f32_16x16x32_bf16(qa1h, kB1h, aB, 0, 0, 0);
    aB = __builtin_amdgcn_mfma_f32_16x16x32_bf16(qa1h, kB1l, aB, 0, 0, 0);
    aB = __builtin_amdgcn_mfma_f32_16x16x32_bf16(qa1l, kB1h, aB, 0, 0, 0);

    float sA[4], sB[4], sc[4];
    #pragma unroll
    for (int r = 0; r < 4; ++r) {
      const int ib = (bh * 512 + i0 + blk * 4 + r) * 512;
      sA[r] = aA[r] + bf2f(bias[ib + j0 + jc]);
      sB[r] = aB[r] + bf2f(bias[ib + j0 + 16 + jc]);
    }
    #pragma unroll
    for (int r = 0; r < 4; ++r) {
      float mx = fmaxf(sA[r], sB[r]);
      mx = fmaxf(mx, __shfl_xor(mx, 1, 64));
      mx = fmaxf(mx, __shfl_xor(mx, 2, 64));
      mx = fmaxf(mx, __shfl_xor(mx, 4, 64));
      mx = fmaxf(mx, __shfl_xor(mx, 8, 64));
      float mn = fmaxf(m[r], mx);
      sc[r] = __expf(m[r] - mn);
      m[r] = mn;
      float pA = __expf(sA[r] - mn);
      float pB = __expf(sB[r] - mn);
      float ps = pA + pB;
      ps += __shfl_xor(ps, 1, 64);
      ps += __shfl_xor(ps, 2, 64);
      ps += __shfl_xor(ps, 4, 64);
      ps += __shfl_xor(ps, 8, 64);
      l[r] = l[r] * sc[r] + ps;
      pw[(blk * 4 + r) * 32 + jc] = f2bf(pA);
      pw[(blk * 4 + r) * 32 + 16 + jc] = f2bf(pB);
    }
    #pragma unroll
    for (int dt = 0; dt < 4; ++dt)
      #pragma unroll
      for (int r = 0; r < 4; ++r)
        o[dt][r] *= sc[r];
    // PV (A = P from LDS, B = Vt direct)
    bf16x8 pf = *(const bf16x8*)&pw[jc * 32 + blk * 8];
    #pragma unroll
    for (int dt = 0; dt < 4; ++dt) {
      const int va = (bh * 64 + dt * 16 + jc) * 512 + j0 + blk * 8;
      bf16x8 vh = *(const bf16x8*)&vthi[va];
      bf16x8 vl = *(const bf16x8*)&vtlo[va];
      o[dt] = __builtin_amdgcn_mfma_f32_16x16x32_bf16(pf, vh, o[dt], 0, 0, 0);
      o[dt] = __builtin_amdgcn_mfma_f32_16x16x32_bf16(pf, vl, o[dt], 0, 0, 0);
    }
  }
  // write partials
  #pragma unroll
  for (int dt = 0; dt < 4; ++dt)
    #pragma unroll
    for (int r = 0; r < 4; ++r)
      olds[(w * 16 + blk * 4 + r) * 65 + dt * 16 + jc] = o[dt][r];
  if (jc == 0) {
    #pragma unroll
    for (int r = 0; r < 4; ++r) {
      mls[(w * 16 + blk * 4 + r) * 2 + 0] = m[r];
      mls[(w * 16 + blk * 4 + r) * 2 + 1] = l[r];
    }
  }
  __syncthreads();
  // merge the 8 j-partials
  #pragma unroll
  for (int itx = 0; itx < 2; ++itx) {
    int idx = tid + itx * 512;
    int q = idx >> 6, d = idx & 63;
    float M = -1e30f;
    #pragma unroll
    for (int ww = 0; ww < 8; ++ww) M = fmaxf(M, mls[(ww * 16 + q) * 2]);
    float L = 0.f, acc = 0.f;
    #pragma unroll
    for (int ww = 0; ww < 8; ++ww) {
      float e = __expf(mls[(ww * 16 + q) * 2] - M);
      L += mls[(ww * 16 + q) * 2 + 1] * e;
      acc += olds[(ww * 16 + q) * 65 + d] * e;
    }
    ao[(b * 512 + i0 + q) * 512 + h * 64 + d] = acc / L;
  }
}

// ---------------- K4: output GEMM  out = ao[1024,512] @ Wout + bout ---------
__global__ __launch_bounds__(256) void k_out(const float* __restrict__ A,
                                             const float* __restrict__ W,
                                             const float* __restrict__ bout,
                                             float* __restrict__ out) {
  __shared__ __align__(16) float As[32][68];
  __shared__ __align__(16) float Bs[32][64];
  const int bid = blockIdx.x;
  const int mt = bid >> 3, nt = bid & 7;
  const int m0 = mt * 64, n0 = nt * 64;
  const int t = threadIdx.x;
  const int tm = t >> 4, tn = t & 15;
  float acc[4][4] = {};
  for (int k0 = 0; k0 < 512; k0 += 32) {
    #pragma unroll
    for (int c = 0; c < 2; ++c) {
      int idx = t + c * 256;
      int m = idx >> 3, k4 = idx & 7;
      const float4 a = *(const float4*)&A[(m0 + m) * 512 + k0 + k4 * 4];
      As[k4 * 4 + 0][m] = a.x; As[k4 * 4 + 1][m] = a.y;
      As[k4 * 4 + 2][m] = a.z; As[k4 * 4 + 3][m] = a.w;
    }
    #pragma unroll
    for (int c = 0; c < 2; ++c) {
      int idx = t + c * 256;
      int kk = idx >> 4, n4 = idx & 15;
      *(float4*)&Bs[kk][n4 * 4] = *(const float4*)&W[(k0 + kk) * 512 + n0 + n4 * 4];
    }
    __syncthreads();
    #pragma unroll
    for (int kk = 0; kk < 32; ++kk) {
      const float4 a4 = *(const float4*)&As[kk][tm * 4];
      const float4 b4 = *(const float4*)&Bs[kk][tn * 4];
      float ra[4] = {a4.x, a4.y, a4.z, a4.w};
      float rb[4] = {b4.x, b4.y, b4.z, b4.w};
      #pragma unroll
      for (int ii = 0; ii < 4; ++ii)
        #pragma unroll
        for (int jj = 0; jj < 4; ++jj)
          acc[ii][jj] = fmaf(ra[ii], rb[jj], acc[ii][jj]);
    }
    __syncthreads();
  }
  const float4 bb = *(const float4*)&bout[n0 + tn * 4];
  #pragma unroll
  for (int ii = 0; ii < 4; ++ii) {
    int row = m0 + tm * 4 + ii;
    float4 o4 = make_float4(acc[ii][0] + bb.x, acc[ii][1] + bb.y,
                            acc[ii][2] + bb.z, acc[ii][3] + bb.w);
    *(float4*)&out[row * 512 + n0 + tn * 4] = o4;
  }
}

extern "C" void kernel_launch(void* const* d_in, const int* in_sizes, int n_in,
                              void* d_out, int out_size, void* d_ws, size_t ws_size,
                              hipStream_t stream) {
  const float* x    = (const float*)d_in[0];
  const float* pos  = (const float*)d_in[1];
  const float* Wqkv = (const float*)d_in[2];
  const float* Wout = (const float*)d_in[3];
  const float* bout = (const float*)d_in[4];
  const float* W1   = (const float*)d_in[5];
  const float* b1   = (const float*)d_in[6];
  const float* W2   = (const float*)d_in[7];
  const float* b2   = (const float*)d_in[8];
  float* out = (float*)d_out;
  char* base = (char*)d_ws;

  __half* Tx = (__half*)(base);                              // 262144 B
  __half* Ty = (__half*)(base + 262144);                     // 262144 B
  unsigned short* qhi  = (unsigned short*)(base + 524288);   // 1 MB each
  unsigned short* qlo  = (unsigned short*)(base + 1572864);
  unsigned short* khi  = (unsigned short*)(base + 2621440);
  unsigned short* klo  = (unsigned short*)(base + 3670016);
  unsigned short* vthi = (unsigned short*)(base + 4718592);
  unsigned short* vtlo = (unsigned short*)(base + 5767168);
  unsigned short* bias = (unsigned short*)(base + 6815744);  // 8388608 B
  float* ao = (float*)(base + 15204352);                     // 2097152 B

  hipLaunchKernelGGL(k_qkv,  dim3(384),  dim3(256), 0, stream,
                     x, Wqkv, qhi, qlo, khi, klo, vthi, vtlo);
  hipLaunchKernelGGL(k_tab,  dim3(1024), dim3(256), 0, stream, W1, b1, Tx, Ty);
  hipLaunchKernelGGL(k_bias, dim3(2048), dim3(256), 0, stream,
                     pos, Tx, Ty, W2, b2, bias);
  hipLaunchKernelGGL(k_attn, dim3(512),  dim3(512), 0, stream,
                     qhi, qlo, khi, klo, vthi, vtlo, bias, ao);
  hipLaunchKernelGGL(k_out,  dim3(128),  dim3(256), 0, stream, ao, Wout, bout, out);
}

// Round 3
// 63.732 us; speedup vs baseline: 2.6168x; 1.5898x over previous
//
#include <hip/hip_runtime.h>
#include <hip/hip_fp16.h>
#include <math.h>

typedef __attribute__((ext_vector_type(8))) short bf16x8;
typedef __attribute__((ext_vector_type(4))) float f32x4;

#define TBL 1024
#define UMAXV (1.0f/11.0f)

__device__ __forceinline__ unsigned short f2bf(float f) {
  unsigned u = __builtin_bit_cast(unsigned, f);
  u = (u + 0x7fffu + ((u >> 16) & 1u)) >> 16;
  return (unsigned short)u;
}
__device__ __forceinline__ float bf2f(unsigned short s) {
  unsigned u = ((unsigned)s) << 16;
  return __builtin_bit_cast(float, u);
}
__device__ __forceinline__ void split2(float f, unsigned short& hi, unsigned short& lo) {
  hi = f2bf(f);
  lo = f2bf(f - bf2f(hi));
}
// swizzled 16B-quad element index within a [rows][64-bf16] LDS tile
__device__ __forceinline__ int swq(int row, int q) {
  return row * 64 + ((q ^ (row & 7)) << 3);
}

// ---------------- K0: split x to bf16 hi/lo; transpose+split Wqkv, Wout -----
__global__ __launch_bounds__(256) void k_split(
    const float* __restrict__ x, const float* __restrict__ Wqkv,
    const float* __restrict__ Wout,
    unsigned short* __restrict__ xh, unsigned short* __restrict__ xl,
    unsigned short* __restrict__ Wth, unsigned short* __restrict__ Wtl,
    unsigned short* __restrict__ Woth, unsigned short* __restrict__ Wotl) {
  __shared__ float Tt[32 * 33];
  const int t = threadIdx.x;
  const int bid = blockIdx.x;
  if (bid < 512) {                       // x: 1024x512 straight split
    int e = (bid * 256 + t) * 4;
    float4 v = *(const float4*)&x[e];
    ushort4 h, l;
    split2(v.x, h.x, l.x); split2(v.y, h.y, l.y);
    split2(v.z, h.z, l.z); split2(v.w, h.w, l.w);
    *(ushort4*)&xh[e] = h;
    *(ushort4*)&xl[e] = l;
    return;
  }
  int k0, n0, ncols;
  const float* W;
  unsigned short *Oh, *Ol;
  if (bid < 1280) {                      // Wqkv: 512x1536 -> Wt[1536][512]
    int tile = bid - 512;
    k0 = (tile / 48) * 32; n0 = (tile % 48) * 32; ncols = 1536;
    W = Wqkv; Oh = Wth; Ol = Wtl;
  } else {                               // Wout: 512x512 -> Wot[512][512]
    int tile = bid - 1280;
    k0 = (tile / 16) * 32; n0 = (tile % 16) * 32; ncols = 512;
    W = Wout; Oh = Woth; Ol = Wotl;
  }
  {
    int kl = t >> 3, nl = (t & 7) * 4;
    float4 v = *(const float4*)&W[(k0 + kl) * ncols + n0 + nl];
    Tt[kl * 33 + nl + 0] = v.x;
    Tt[kl * 33 + nl + 1] = v.y;
    Tt[kl * 33 + nl + 2] = v.z;
    Tt[kl * 33 + nl + 3] = v.w;
  }
  __syncthreads();
  {
    int nl = t >> 3, kq = (t & 7) * 4;
    ushort4 h, l;
    split2(Tt[(kq + 0) * 33 + nl], h.x, l.x);
    split2(Tt[(kq + 1) * 33 + nl], h.y, l.y);
    split2(Tt[(kq + 2) * 33 + nl], h.z, l.z);
    split2(Tt[(kq + 3) * 33 + nl], h.w, l.w);
    int o = (n0 + nl) * 512 + k0 + kq;
    *(ushort4*)&Oh[o] = h;
    *(ushort4*)&Ol[o] = l;
  }
}

// ---------------- K1: QKV GEMM via MFMA bf16 hi/lo split --------------------
// C[1024,1536] = x @ Wqkv; emits q/k hi+lo [B,H,N,64] (q scaled 1/8),
// v transposed hi+lo [B,H,64,N]
__global__ __launch_bounds__(256) void k_qkv(
    const unsigned short* __restrict__ xh, const unsigned short* __restrict__ xl,
    const unsigned short* __restrict__ Wth, const unsigned short* __restrict__ Wtl,
    unsigned short* __restrict__ qhi, unsigned short* __restrict__ qlo,
    unsigned short* __restrict__ khi, unsigned short* __restrict__ klo,
    unsigned short* __restrict__ vthi, unsigned short* __restrict__ vtlo) {
  __shared__ __align__(16) unsigned short SM[16384];   // 32 KB
  unsigned short* Ah = SM;
  unsigned short* Al = SM + 4096;
  unsigned short* Bh = SM + 8192;
  unsigned short* Bl = SM + 12288;

  const int bid = blockIdx.x;            // 16*24
  const int mt = bid / 24, nt = bid % 24;
  const int m0 = mt * 64, n0 = nt * 64;
  const int t = threadIdx.x;
  const int w = t >> 6, lane = t & 63, blk = lane >> 4, jc = lane & 15;
  const int mw = (w & 1) * 32, nw = (w >> 1) * 32;
  const int sm = t >> 3, sq = t & 7;     // staging coords

  f32x4 acc[2][2];
  #pragma unroll
  for (int i = 0; i < 2; ++i)
    #pragma unroll
    for (int j = 0; j < 2; ++j) acc[i][j] = f32x4{0.f, 0.f, 0.f, 0.f};

  bf16x8 pa[2], pal[2], pb[2], pbl[2];
  #pragma unroll
  for (int c = 0; c < 2; ++c) {
    int off = (m0 + sm + c * 32) * 512 + sq * 8;
    int ofb = (n0 + sm + c * 32) * 512 + sq * 8;
    pa[c]  = *(const bf16x8*)&xh[off];
    pal[c] = *(const bf16x8*)&xl[off];
    pb[c]  = *(const bf16x8*)&Wth[ofb];
    pbl[c] = *(const bf16x8*)&Wtl[ofb];
  }
  for (int it = 0; it < 8; ++it) {
    #pragma unroll
    for (int c = 0; c < 2; ++c) {
      int a = swq(sm + c * 32, sq);
      *(bf16x8*)&Ah[a] = pa[c];
      *(bf16x8*)&Al[a] = pal[c];
      *(bf16x8*)&Bh[a] = pb[c];
      *(bf16x8*)&Bl[a] = pbl[c];
    }
    __syncthreads();
    if (it < 7) {
      int k0 = (it + 1) * 64;
      #pragma unroll
      for (int c = 0; c < 2; ++c) {
        int off = (m0 + sm + c * 32) * 512 + k0 + sq * 8;
        int ofb = (n0 + sm + c * 32) * 512 + k0 + sq * 8;
        pa[c]  = *(const bf16x8*)&xh[off];
        pal[c] = *(const bf16x8*)&xl[off];
        pb[c]  = *(const bf16x8*)&Wth[ofb];
        pbl[c] = *(const bf16x8*)&Wtl[ofb];
      }
    }
    #pragma unroll
    for (int h = 0; h < 2; ++h) {
      int q = h * 4 + blk;
      bf16x8 a0h = *(const bf16x8*)&Ah[swq(mw + jc, q)];
      bf16x8 a0l = *(const bf16x8*)&Al[swq(mw + jc, q)];
      bf16x8 a1h = *(const bf16x8*)&Ah[swq(mw + 16 + jc, q)];
      bf16x8 a1l = *(const bf16x8*)&Al[swq(mw + 16 + jc, q)];
      bf16x8 b0h = *(const bf16x8*)&Bh[swq(nw + jc, q)];
      bf16x8 b0l = *(const bf16x8*)&Bl[swq(nw + jc, q)];
      bf16x8 b1h = *(const bf16x8*)&Bh[swq(nw + 16 + jc, q)];
      bf16x8 b1l = *(const bf16x8*)&Bl[swq(nw + 16 + jc, q)];
      acc[0][0] = __builtin_amdgcn_mfma_f32_16x16x32_bf16(a0h, b0h, acc[0][0], 0, 0, 0);
      acc[0][0] = __builtin_amdgcn_mfma_f32_16x16x32_bf16(a0h, b0l, acc[0][0], 0, 0, 0);
      acc[0][0] = __builtin_amdgcn_mfma_f32_16x16x32_bf16(a0l, b0h, acc[0][0], 0, 0, 0);
      acc[0][1] = __builtin_amdgcn_mfma_f32_16x16x32_bf16(a0h, b1h, acc[0][1], 0, 0, 0);
      acc[0][1] = __builtin_amdgcn_mfma_f32_16x16x32_bf16(a0h, b1l, acc[0][1], 0, 0, 0);
      acc[0][1] = __builtin_amdgcn_mfma_f32_16x16x32_bf16(a0l, b1h, acc[0][1], 0, 0, 0);
      acc[1][0] = __builtin_amdgcn_mfma_f32_16x16x32_bf16(a1h, b0h, acc[1][0], 0, 0, 0);
      acc[1][0] = __builtin_amdgcn_mfma_f32_16x16x32_bf16(a1h, b0l, acc[1][0], 0, 0, 0);
      acc[1][0] = __builtin_amdgcn_mfma_f32_16x16x32_bf16(a1l, b0h, acc[1][0], 0, 0, 0);
      acc[1][1] = __builtin_amdgcn_mfma_f32_16x16x32_bf16(a1h, b1h, acc[1][1], 0, 0, 0);
      acc[1][1] = __builtin_amdgcn_mfma_f32_16x16x32_bf16(a1h, b1l, acc[1][1], 0, 0, 0);
      acc[1][1] = __builtin_amdgcn_mfma_f32_16x16x32_bf16(a1l, b1h, acc[1][1], 0, 0, 0);
    }
    __syncthreads();
  }
  const int sec = n0 >> 9;
  const int hh_ = (n0 >> 6) & 7;
  if (sec < 2) {
    unsigned short* dh = (sec == 0) ? qhi : khi;
    unsigned short* dl = (sec == 0) ? qlo : klo;
    const float scl = (sec == 0) ? 0.125f : 1.0f;
    #pragma unroll
    for (int i = 0; i < 2; ++i)
      #pragma unroll
      for (int j = 0; j < 2; ++j)
        #pragma unroll
        for (int r = 0; r < 4; ++r) {
          int tok = m0 + mw + i * 16 + blk * 4 + r;
          int b = tok >> 9, nn = tok & 511;
          int d = nw + j * 16 + jc;
          unsigned short h, l;
          split2(acc[i][j][r] * scl, h, l);
          int addr = ((b * 8 + hh_) * 512 + nn) * 64 + d;
          dh[addr] = h;
          dl[addr] = l;
        }
  } else {
    float* T = (float*)SM;               // [64 d][68 tok] fp32 = 17408 B
    #pragma unroll
    for (int i = 0; i < 2; ++i)
      #pragma unroll
      for (int j = 0; j < 2; ++j)
        #pragma unroll
        for (int r = 0; r < 4; ++r)
          T[(nw + j * 16 + jc) * 68 + mw + i * 16 + blk * 4 + r] = acc[i][j][r];
    __syncthreads();
    const int d = t >> 2, nq = (t & 3) * 16;
    const int b = m0 >> 9, nb = m0 & 511;
    #pragma unroll
    for (int c = 0; c < 4; ++c) {
      float4 vv = *(float4*)&T[d * 68 + nq + c * 4];
      ushort4 hv, lv;
      split2(vv.x, hv.x, lv.x); split2(vv.y, hv.y, lv.y);
      split2(vv.z, hv.z, lv.z); split2(vv.w, hv.w, lv.w);
      int addr = ((b * 8 + hh_) * 64 + d) * 512 + nb + nq + c * 4;
      *(ushort4*)&vthi[addr] = hv;
      *(ushort4*)&vtlo[addr] = lv;
    }
  }
}

// ---------------- K2a: RPE hidden-layer tables ------------------------------
__global__ __launch_bounds__(256) void k_tab(const float* __restrict__ W1,
                                             const float* __restrict__ b1,
                                             __half* __restrict__ Tx,
                                             __half* __restrict__ Ty) {
  int gid = blockIdx.x * 256 + threadIdx.x;   // TBL*32
  int e = gid >> 5, c = gid & 31;
  float u = -UMAXV + (2.0f * UMAXV) * (float)e / (float)(TBL - 1);
  const int xpart = (c < 16);
  const int col = c & 15;
  const int base = xpart ? 0 : 65;
  float sum = u * W1[base * 16 + col] + (xpart ? b1[col] : 0.0f);
  float s1, c1;
  sincosf(u * 3.14159265358979323846f, &s1, &c1);
  float sk = s1, ck = c1;
  for (int k = 1; k <= 32; ++k) {
    sum += sk * W1[(base + k) * 16 + col] + ck * W1[(base + 32 + k) * 16 + col];
    float ns = sk * c1 + ck * s1;
    ck = ck * c1 - sk * s1;
    sk = ns;
  }
  (xpart ? Tx : Ty)[e * 16 + col] = __float2half(sum);
}

// ---------------- K2b: RPE bias via table lookup -> bias bf16 [B,H,N,N] ------
__global__ __launch_bounds__(256) void k_bias(const float* __restrict__ pos,
                                              const __half* __restrict__ Tx,
                                              const __half* __restrict__ Ty,
                                              const float* __restrict__ W2,
                                              const float* __restrict__ b2,
                                              unsigned short* __restrict__ bias) {
  const int gid = blockIdx.x * 256 + threadIdx.x;   // < 524288
  const int b = gid >> 18;
  const int i = (gid >> 9) & 511;
  const int j = gid & 511;
  const float pix = pos[(b * 512 + i) * 2 + 0];
  const float piy = pos[(b * 512 + i) * 2 + 1];
  const float pjx = pos[(b * 512 + j) * 2 + 0];
  const float pjy = pos[(b * 512 + j) * 2 + 1];
  float txv = (pjx - pix) * 0.1f; float ux = txv / (1.0f + fabsf(txv));
  float tyv = (pjy - piy) * 0.1f; float uy = tyv / (1.0f + fabsf(tyv));
  const float invstep = (float)(TBL - 1) / (2.0f * UMAXV);
  float fx = (ux + UMAXV) * invstep;
  int ix = (int)fx; ix = min(max(ix, 0), TBL - 2);
  float wx = fx - (float)ix;
  float fy = (uy + UMAXV) * invstep;
  int iy = (int)fy; iy = min(max(iy, 0), TBL - 2);
  float wy = fy - (float)iy;

  __half hx0[16], hx1[16], hy0[16], hy1[16];
  *(uint4*)&hx0[0] = *(const uint4*)&Tx[ix * 16];
  *(uint4*)&hx0[8] = *(const uint4*)&Tx[ix * 16 + 8];
  *(uint4*)&hx1[0] = *(const uint4*)&Tx[(ix + 1) * 16];
  *(uint4*)&hx1[8] = *(const uint4*)&Tx[(ix + 1) * 16 + 8];
  *(uint4*)&hy0[0] = *(const uint4*)&Ty[iy * 16];
  *(uint4*)&hy0[8] = *(const uint4*)&Ty[iy * 16 + 8];
  *(uint4*)&hy1[0] = *(const uint4*)&Ty[(iy + 1) * 16];
  *(uint4*)&hy1[8] = *(const uint4*)&Ty[(iy + 1) * 16 + 8];

  float o[8];
  #pragma unroll
  for (int c = 0; c < 8; ++c) o[c] = b2[c];
  #pragma unroll
  for (int r = 0; r < 16; ++r) {
    float ax = __half2float(hx0[r]);
    float bx = __half2float(hx1[r]);
    float ay = __half2float(hy0[r]);
    float by = __half2float(hy1[r]);
    float hv = fmaf(wx, bx - ax, ax) + fmaf(wy, by - ay, ay);
    float z = hv * 0.70710678118654752f;
    float az = fabsf(z);
    float tt = __builtin_amdgcn_rcpf(fmaf(0.3275911f, az, 1.0f));
    float poly = ((((1.061405429f * tt - 1.453152027f) * tt + 1.421413741f) * tt
                   - 0.284496736f) * tt + 0.254829592f) * tt;
    float ex = __expf(-z * z);
    float erfv = copysignf(fmaf(-poly, ex, 1.0f), z);
    float g = 0.5f * hv * (1.0f + erfv);
    #pragma unroll
    for (int c = 0; c < 8; ++c)
      o[c] = fmaf(g, W2[r * 8 + c], o[c]);
  }
  #pragma unroll
  for (int c = 0; c < 8; ++c)
    bias[((b * 8 + c) * 512 + i) * 512 + j] = f2bf(o[c]);
}

// ---------------- K3: MFMA flash attention ----------------------------------
__global__ __launch_bounds__(512) void k_attn(
    const unsigned short* __restrict__ qhi, const unsigned short* __restrict__ qlo,
    const unsigned short* __restrict__ khi, const unsigned short* __restrict__ klo,
    const unsigned short* __restrict__ vthi, const unsigned short* __restrict__ vtlo,
    const unsigned short* __restrict__ bias,
    unsigned short* __restrict__ aoh, unsigned short* __restrict__ aol) {
  __shared__ __align__(16) unsigned short psu[8 * 512];
  __shared__ __align__(16) float olds[8 * 16 * 65];
  __shared__ float mls[8 * 16 * 2];

  const int bid = blockIdx.x;
  const int it = bid & 31, h = (bid >> 5) & 7, b = bid >> 8;
  const int i0 = it * 16;
  const int bh = b * 8 + h;
  const int tid = threadIdx.x;
  const int w = tid >> 6, lane = tid & 63;
  const int blk = lane >> 4, jc = lane & 15;

  const int qoff = (bh * 512 + i0 + jc) * 64 + blk * 8;
  const bf16x8 qa0h = *(const bf16x8*)&qhi[qoff];
  const bf16x8 qa1h = *(const bf16x8*)&qhi[qoff + 32];
  const bf16x8 qa0l = *(const bf16x8*)&qlo[qoff];
  const bf16x8 qa1l = *(const bf16x8*)&qlo[qoff + 32];

  float m[4] = {-1e30f, -1e30f, -1e30f, -1e30f};
  float l[4] = {0.f, 0.f, 0.f, 0.f};
  f32x4 o[4];
  #pragma unroll
  for (int dt = 0; dt < 4; ++dt) o[dt] = f32x4{0.f, 0.f, 0.f, 0.f};

  unsigned short* pw = &psu[w * 512];

  #pragma unroll
  for (int jt = 0; jt < 2; ++jt) {
    const int j0 = w * 64 + jt * 32;
    const int rA = (bh * 512 + j0 + jc) * 64 + blk * 8;
    const int rB = rA + 16 * 64;
    bf16x8 kA0h = *(const bf16x8*)&khi[rA];
    bf16x8 kA1h = *(const bf16x8*)&khi[rA + 32];
    bf16x8 kA0l = *(const bf16x8*)&klo[rA];
    bf16x8 kA1l = *(const bf16x8*)&klo[rA + 32];
    bf16x8 kB0h = *(const bf16x8*)&khi[rB];
    bf16x8 kB1h = *(const bf16x8*)&khi[rB + 32];
    bf16x8 kB0l = *(const bf16x8*)&klo[rB];
    bf16x8 kB1l = *(const bf16x8*)&klo[rB + 32];

    f32x4 aA = {0.f, 0.f, 0.f, 0.f};
    aA = __builtin_amdgcn_mfma_f32_16x16x32_bf16(qa0h, kA0h, aA, 0, 0, 0);
    aA = __builtin_amdgcn_mfma_f32_16x16x32_bf16(qa0h, kA0l, aA, 0, 0, 0);
    aA = __builtin_amdgcn_mfma_f32_16x16x32_bf16(qa0l, kA0h, aA, 0, 0, 0);
    aA = __builtin_amdgcn_mfma_f32_16x16x32_bf16(qa1h, kA1h, aA, 0, 0, 0);
    aA = __builtin_amdgcn_mfma_f32_16x16x32_bf16(qa1h, kA1l, aA, 0, 0, 0);
    aA = __builtin_amdgcn_mfma_f32_16x16x32_bf16(qa1l, kA1h, aA, 0, 0, 0);
    f32x4 aB = {0.f, 0.f, 0.f, 0.f};
    aB = __builtin_amdgcn_mfma_f32_16x16x32_bf16(qa0h, kB0h, aB, 0, 0, 0);
    aB = __builtin_amdgcn_mfma_f32_16x16x32_bf16(qa0h, kB0l, aB, 0, 0, 0);
    aB = __builtin_amdgcn_mfma_f32_16x16x32_bf16(qa0l, kB0h, aB, 0, 0, 0);
    aB = __builtin_amdgcn_mfma_f32_16x16x32_bf16(qa1h, kB1h, aB, 0, 0, 0);
    aB = __builtin_amdgcn_mfma_f32_16x16x32_bf16(qa1h, kB1l, aB, 0, 0, 0);
    aB = __builtin_amdgcn_mfma_f32_16x16x32_bf16(qa1l, kB1h, aB, 0, 0, 0);

    float sA[4], sB[4], sc[4];
    #pragma unroll
    for (int r = 0; r < 4; ++r) {
      const int ib = (bh * 512 + i0 + blk * 4 + r) * 512;
      sA[r] = aA[r] + bf2f(bias[ib + j0 + jc]);
      sB[r] = aB[r] + bf2f(bias[ib + j0 + 16 + jc]);
    }
    #pragma unroll
    for (int r = 0; r < 4; ++r) {
      float mx = fmaxf(sA[r], sB[r]);
      mx = fmaxf(mx, __shfl_xor(mx, 1, 64));
      mx = fmaxf(mx, __shfl_xor(mx, 2, 64));
      mx = fmaxf(mx, __shfl_xor(mx, 4, 64));
      mx = fmaxf(mx, __shfl_xor(mx, 8, 64));
      float mn = fmaxf(m[r], mx);
      sc[r] = __expf(m[r] - mn);
      m[r] = mn;
      float pA = __expf(sA[r] - mn);
      float pB = __expf(sB[r] - mn);
      float ps = pA + pB;
      ps += __shfl_xor(ps, 1, 64);
      ps += __shfl_xor(ps, 2, 64);
      ps += __shfl_xor(ps, 4, 64);
      ps += __shfl_xor(ps, 8, 64);
      l[r] = l[r] * sc[r] + ps;
      pw[(blk * 4 + r) * 32 + jc] = f2bf(pA);
      pw[(blk * 4 + r) * 32 + 16 + jc] = f2bf(pB);
    }
    #pragma unroll
    for (int dt = 0; dt < 4; ++dt)
      #pragma unroll
      for (int r = 0; r < 4; ++r)
        o[dt][r] *= sc[r];
    bf16x8 pf = *(const bf16x8*)&pw[jc * 32 + blk * 8];
    #pragma unroll
    for (int dt = 0; dt < 4; ++dt) {
      const int va = (bh * 64 + dt * 16 + jc) * 512 + j0 + blk * 8;
      bf16x8 vh = *(const bf16x8*)&vthi[va];
      bf16x8 vl = *(const bf16x8*)&vtlo[va];
      o[dt] = __builtin_amdgcn_mfma_f32_16x16x32_bf16(pf, vh, o[dt], 0, 0, 0);
      o[dt] = __builtin_amdgcn_mfma_f32_16x16x32_bf16(pf, vl, o[dt], 0, 0, 0);
    }
  }
  #pragma unroll
  for (int dt = 0; dt < 4; ++dt)
    #pragma unroll
    for (int r = 0; r < 4; ++r)
      olds[(w * 16 + blk * 4 + r) * 65 + dt * 16 + jc] = o[dt][r];
  if (jc == 0) {
    #pragma unroll
    for (int r = 0; r < 4; ++r) {
      mls[(w * 16 + blk * 4 + r) * 2 + 0] = m[r];
      mls[(w * 16 + blk * 4 + r) * 2 + 1] = l[r];
    }
  }
  __syncthreads();
  #pragma unroll
  for (int itx = 0; itx < 2; ++itx) {
    int idx = tid + itx * 512;
    int q = idx >> 6, d = idx & 63;
    float M = -1e30f;
    #pragma unroll
    for (int ww = 0; ww < 8; ++ww) M = fmaxf(M, mls[(ww * 16 + q) * 2]);
    float L = 0.f, acc = 0.f;
    #pragma unroll
    for (int ww = 0; ww < 8; ++ww) {
      float e = __expf(mls[(ww * 16 + q) * 2] - M);
      L += mls[(ww * 16 + q) * 2 + 1] * e;
      acc += olds[(ww * 16 + q) * 65 + d] * e;
    }
    unsigned short oh, ol;
    split2(acc / L, oh, ol);
    int addr = (b * 512 + i0 + q) * 512 + h * 64 + d;
    aoh[addr] = oh;
    aol[addr] = ol;
  }
}

// ---------------- K4: output GEMM via MFMA  out = ao @ Wout + bout ----------
__global__ __launch_bounds__(256) void k_out(
    const unsigned short* __restrict__ aoh, const unsigned short* __restrict__ aol,
    const unsigned short* __restrict__ Wh, const unsigned short* __restrict__ Wl,
    const float* __restrict__ bout, float* __restrict__ out) {
  __shared__ __align__(16) unsigned short SM[12288];   // 24 KB
  unsigned short* Ah = SM;                             // [32][64]
  unsigned short* Al = SM + 2048;
  unsigned short* Bh = SM + 4096;                      // [64][64]
  unsigned short* Bl = SM + 8192;

  const int bid = blockIdx.x;            // 32*8
  const int mt = bid >> 3, nt = bid & 7;
  const int m0 = mt * 32, n0 = nt * 64;
  const int t = threadIdx.x;
  const int w = t >> 6, lane = t & 63, blk = lane >> 4, jc = lane & 15;
  const int mh_ = (w & 1) * 16, nh_ = (w >> 1) * 32;
  const int sm = t >> 3, sq = t & 7;     // sm: 0..31

  f32x4 acc[2];
  acc[0] = f32x4{0.f, 0.f, 0.f, 0.f};
  acc[1] = f32x4{0.f, 0.f, 0.f, 0.f};

  bf16x8 pa, pal, pb[2], pbl[2];
  {
    int off = (m0 + sm) * 512 + sq * 8;
    pa  = *(const bf16x8*)&aoh[off];
    pal = *(const bf16x8*)&aol[off];
    #pragma unroll
    for (int c = 0; c < 2; ++c) {
      int ofb = (n0 + sm + c * 32) * 512 + sq * 8;
      pb[c]  = *(const bf16x8*)&Wh[ofb];
      pbl[c] = *(const bf16x8*)&Wl[ofb];
    }
  }
  for (int it = 0; it < 8; ++it) {
    {
      int a = swq(sm, sq);
      *(bf16x8*)&Ah[a] = pa;
      *(bf16x8*)&Al[a] = pal;
      #pragma unroll
      for (int c = 0; c < 2; ++c) {
        int bca = swq(sm + c * 32, sq);
        *(bf16x8*)&Bh[bca] = pb[c];
        *(bf16x8*)&Bl[bca] = pbl[c];
      }
    }
    __syncthreads();
    if (it < 7) {
      int k0 = (it + 1) * 64;
      int off = (m0 + sm) * 512 + k0 + sq * 8;
      pa  = *(const bf16x8*)&aoh[off];
      pal = *(const bf16x8*)&aol[off];
      #pragma unroll
      for (int c = 0; c < 2; ++c) {
        int ofb = (n0 + sm + c * 32) * 512 + k0 + sq * 8;
        pb[c]  = *(const bf16x8*)&Wh[ofb];
        pbl[c] = *(const bf16x8*)&Wl[ofb];
      }
    }
    #pragma unroll
    for (int h = 0; h < 2; ++h) {
      int q = h * 4 + blk;
      bf16x8 a0h = *(const bf16x8*)&Ah[swq(mh_ + jc, q)];
      bf16x8 a0l = *(const bf16x8*)&Al[swq(mh_ + jc, q)];
      bf16x8 b0h = *(const bf16x8*)&Bh[swq(nh_ + jc, q)];
      bf16x8 b0l = *(const bf16x8*)&Bl[swq(nh_ + jc, q)];
      bf16x8 b1h = *(const bf16x8*)&Bh[swq(nh_ + 16 + jc, q)];
      bf16x8 b1l = *(const bf16x8*)&Bl[swq(nh_ + 16 + jc, q)];
      acc[0] = __builtin_amdgcn_mfma_f32_16x16x32_bf16(a0h, b0h, acc[0], 0, 0, 0);
      acc[0] = __builtin_amdgcn_mfma_f32_16x16x32_bf16(a0h, b0l, acc[0], 0, 0, 0);
      acc[0] = __builtin_amdgcn_mfma_f32_16x16x32_bf16(a0l, b0h, acc[0], 0, 0, 0);
      acc[1] = __builtin_amdgcn_mfma_f32_16x16x32_bf16(a0h, b1h, acc[1], 0, 0, 0);
      acc[1] = __builtin_amdgcn_mfma_f32_16x16x32_bf16(a0h, b1l, acc[1], 0, 0, 0);
      acc[1] = __builtin_amdgcn_mfma_f32_16x16x32_bf16(a0l, b1h, acc[1], 0, 0, 0);
    }
    __syncthreads();
  }
  #pragma unroll
  for (int j = 0; j < 2; ++j) {
    int n = n0 + nh_ + j * 16 + jc;
    float bb = bout[n];
    #pragma unroll
    for (int r = 0; r < 4; ++r) {
      int row = m0 + mh_ + blk * 4 + r;
      out[row * 512 + n] = acc[j][r] + bb;
    }
  }
}

extern "C" void kernel_launch(void* const* d_in, const int* in_sizes, int n_in,
                              void* d_out, int out_size, void* d_ws, size_t ws_size,
                              hipStream_t stream) {
  const float* x    = (const float*)d_in[0];
  const float* pos  = (const float*)d_in[1];
  const float* Wqkv = (const float*)d_in[2];
  const float* Wout = (const float*)d_in[3];
  const float* bout = (const float*)d_in[4];
  const float* W1   = (const float*)d_in[5];
  const float* b1   = (const float*)d_in[6];
  const float* W2   = (const float*)d_in[7];
  const float* b2   = (const float*)d_in[8];
  float* out = (float*)d_out;
  char* base = (char*)d_ws;

  __half* Tx = (__half*)(base);                                // 32 KB
  __half* Ty = (__half*)(base + 32768);                        // 32 KB
  unsigned short* xh   = (unsigned short*)(base + 65536);      // 1 MB
  unsigned short* xl   = (unsigned short*)(base + 1114112);    // 1 MB
  unsigned short* Wth  = (unsigned short*)(base + 2162688);    // 1.5 MB
  unsigned short* Wtl  = (unsigned short*)(base + 3735552);    // 1.5 MB
  unsigned short* Woth = (unsigned short*)(base + 5308416);    // 512 KB
  unsigned short* Wotl = (unsigned short*)(base + 5832704);    // 512 KB
  unsigned short* qhi  = (unsigned short*)(base + 6356992);    // 1 MB
  unsigned short* qlo  = (unsigned short*)(base + 7405568);
  unsigned short* khi  = (unsigned short*)(base + 8454144);
  unsigned short* klo  = (unsigned short*)(base + 9502720);
  unsigned short* vthi = (unsigned short*)(base + 10551296);
  unsigned short* vtlo = (unsigned short*)(base + 11599872);
  unsigned short* bias = (unsigned short*)(base + 12648448);   // 8 MB
  unsigned short* aoh  = (unsigned short*)(base + 21037056);   // 1 MB
  unsigned short* aol  = (unsigned short*)(base + 22085632);   // 1 MB

  hipLaunchKernelGGL(k_split, dim3(1536), dim3(256), 0, stream,
                     x, Wqkv, Wout, xh, xl, Wth, Wtl, Woth, Wotl);
  hipLaunchKernelGGL(k_tab,  dim3(128),  dim3(256), 0, stream, W1, b1, Tx, Ty);
  hipLaunchKernelGGL(k_bias, dim3(2048), dim3(256), 0, stream,
                     pos, Tx, Ty, W2, b2, bias);
  hipLaunchKernelGGL(k_qkv,  dim3(384),  dim3(256), 0, stream,
                     xh, xl, Wth, Wtl, qhi, qlo, khi, klo, vthi, vtlo);
  hipLaunchKernelGGL(k_attn, dim3(512),  dim3(512), 0, stream,
                     qhi, qlo, khi, klo, vthi, vtlo, bias, aoh, aol);
  hipLaunchKernelGGL(k_out,  dim3(256),  dim3(256), 0, stream,
                     aoh, aol, Woth, Wotl, bout, out);
}

// Round 4
// 54.021 us; speedup vs baseline: 3.0871x; 1.1798x over previous
//
#include <hip/hip_runtime.h>
#include <hip/hip_fp16.h>
#include <math.h>

typedef __attribute__((ext_vector_type(8))) short bf16x8;
typedef __attribute__((ext_vector_type(4))) float f32x4;

#define TBL 512
#define UMAXV (1.0f/11.0f)

__device__ __forceinline__ unsigned short f2bf(float f) {
  unsigned u = __builtin_bit_cast(unsigned, f);
  u = (u + 0x7fffu + ((u >> 16) & 1u)) >> 16;
  return (unsigned short)u;
}
__device__ __forceinline__ float bf2f(unsigned short s) {
  unsigned u = ((unsigned)s) << 16;
  return __builtin_bit_cast(float, u);
}
__device__ __forceinline__ void split2(float f, unsigned short& hi, unsigned short& lo) {
  hi = f2bf(f);
  lo = f2bf(f - bf2f(hi));
}
// swizzled 16B-quad element index within a [rows][64-bf16] LDS tile
__device__ __forceinline__ int swq(int row, int q) {
  return row * 64 + ((q ^ (row & 7)) << 3);
}

// ---------------- K_prep: split x; transpose+split Wqkv/Wout; build tables --
__global__ __launch_bounds__(256) void k_prep(
    const float* __restrict__ x, const float* __restrict__ Wqkv,
    const float* __restrict__ Wout,
    const float* __restrict__ W1, const float* __restrict__ b1,
    unsigned short* __restrict__ xh, unsigned short* __restrict__ xl,
    unsigned short* __restrict__ Wth, unsigned short* __restrict__ Wtl,
    unsigned short* __restrict__ Woth, unsigned short* __restrict__ Wotl,
    __half* __restrict__ Tx, __half* __restrict__ Ty) {
  __shared__ float Tt[32 * 33];
  const int t = threadIdx.x;
  const int bid = blockIdx.x;
  if (bid < 512) {                       // x: 1024x512 straight split
    int e = (bid * 256 + t) * 4;
    float4 v = *(const float4*)&x[e];
    ushort4 h, l;
    split2(v.x, h.x, l.x); split2(v.y, h.y, l.y);
    split2(v.z, h.z, l.z); split2(v.w, h.w, l.w);
    *(ushort4*)&xh[e] = h;
    *(ushort4*)&xl[e] = l;
    return;
  }
  if (bid >= 1536) {                     // hidden-layer tables, TBL*32 threads
    int gid = (bid - 1536) * 256 + t;
    int e = gid >> 5, c = gid & 31;
    float u = -UMAXV + (2.0f * UMAXV) * (float)e / (float)(TBL - 1);
    const int xpart = (c < 16);
    const int col = c & 15;
    const int base = xpart ? 0 : 65;
    float sum = u * W1[base * 16 + col] + (xpart ? b1[col] : 0.0f);
    float s1, c1;
    sincosf(u * 3.14159265358979323846f, &s1, &c1);
    float sk = s1, ck = c1;
    for (int k = 1; k <= 32; ++k) {
      sum += sk * W1[(base + k) * 16 + col] + ck * W1[(base + 32 + k) * 16 + col];
      float ns = sk * c1 + ck * s1;
      ck = ck * c1 - sk * s1;
      sk = ns;
    }
    (xpart ? Tx : Ty)[e * 16 + col] = __float2half(sum);
    return;
  }
  int k0, n0, ncols;
  const float* W;
  unsigned short *Oh, *Ol;
  if (bid < 1280) {                      // Wqkv: 512x1536 -> Wt[1536][512]
    int tile = bid - 512;
    k0 = (tile / 48) * 32; n0 = (tile % 48) * 32; ncols = 1536;
    W = Wqkv; Oh = Wth; Ol = Wtl;
  } else {                               // Wout: 512x512 -> Wot[512][512]
    int tile = bid - 1280;
    k0 = (tile / 16) * 32; n0 = (tile % 16) * 32; ncols = 512;
    W = Wout; Oh = Woth; Ol = Wotl;
  }
  {
    int kl = t >> 3, nl = (t & 7) * 4;
    float4 v = *(const float4*)&W[(k0 + kl) * ncols + n0 + nl];
    Tt[kl * 33 + nl + 0] = v.x;
    Tt[kl * 33 + nl + 1] = v.y;
    Tt[kl * 33 + nl + 2] = v.z;
    Tt[kl * 33 + nl + 3] = v.w;
  }
  __syncthreads();
  {
    int nl = t >> 3, kq = (t & 7) * 4;
    ushort4 h, l;
    split2(Tt[(kq + 0) * 33 + nl], h.x, l.x);
    split2(Tt[(kq + 1) * 33 + nl], h.y, l.y);
    split2(Tt[(kq + 2) * 33 + nl], h.z, l.z);
    split2(Tt[(kq + 3) * 33 + nl], h.w, l.w);
    int o = (n0 + nl) * 512 + k0 + kq;
    *(ushort4*)&Oh[o] = h;
    *(ushort4*)&Ol[o] = l;
  }
}

// ---------------- K_fused: QKV MFMA GEMM (bid<384) + RPE bias (bid>=384) ----
__global__ __launch_bounds__(512) void k_fused(
    const unsigned short* __restrict__ xh, const unsigned short* __restrict__ xl,
    const unsigned short* __restrict__ Wth, const unsigned short* __restrict__ Wtl,
    unsigned short* __restrict__ qhi, unsigned short* __restrict__ qlo,
    unsigned short* __restrict__ khi, unsigned short* __restrict__ klo,
    unsigned short* __restrict__ vthi, unsigned short* __restrict__ vtlo,
    const float* __restrict__ pos,
    const __half* __restrict__ Tx, const __half* __restrict__ Ty,
    const float* __restrict__ W2, const float* __restrict__ b2,
    unsigned short* __restrict__ bias) {
  __shared__ __align__(16) unsigned short SM[16384];   // 32 KB (qkv path only)
  const int bid = blockIdx.x;
  const int t = threadIdx.x;

  if (bid < 384) {
    // ---- QKV GEMM: 64x64 tile, 8 waves (16x32 per wave), K=512 in 8 steps --
    unsigned short* Ah = SM;
    unsigned short* Al = SM + 4096;
    unsigned short* Bh = SM + 8192;
    unsigned short* Bl = SM + 12288;
    const int mt = bid / 24, nt = bid % 24;
    const int m0 = mt * 64, n0 = nt * 64;
    const int w = t >> 6, lane = t & 63, blk = lane >> 4, jc = lane & 15;
    const int mw = (w & 3) * 16, nw = (w >> 2) * 32;
    const int sm_ = t >> 3, sq = t & 7;

    f32x4 acc[2];
    acc[0] = f32x4{0.f, 0.f, 0.f, 0.f};
    acc[1] = f32x4{0.f, 0.f, 0.f, 0.f};

    bf16x8 pa, pal, pb, pbl;
    {
      int off = (m0 + sm_) * 512 + sq * 8;
      int ofb = (n0 + sm_) * 512 + sq * 8;
      pa  = *(const bf16x8*)&xh[off];
      pal = *(const bf16x8*)&xl[off];
      pb  = *(const bf16x8*)&Wth[ofb];
      pbl = *(const bf16x8*)&Wtl[ofb];
    }
    for (int it = 0; it < 8; ++it) {
      {
        int a = swq(sm_, sq);
        *(bf16x8*)&Ah[a] = pa;
        *(bf16x8*)&Al[a] = pal;
        *(bf16x8*)&Bh[a] = pb;
        *(bf16x8*)&Bl[a] = pbl;
      }
      __syncthreads();
      if (it < 7) {
        int k0 = (it + 1) * 64;
        int off = (m0 + sm_) * 512 + k0 + sq * 8;
        int ofb = (n0 + sm_) * 512 + k0 + sq * 8;
        pa  = *(const bf16x8*)&xh[off];
        pal = *(const bf16x8*)&xl[off];
        pb  = *(const bf16x8*)&Wth[ofb];
        pbl = *(const bf16x8*)&Wtl[ofb];
      }
      #pragma unroll
      for (int h = 0; h < 2; ++h) {
        int q = h * 4 + blk;
        bf16x8 a0h = *(const bf16x8*)&Ah[swq(mw + jc, q)];
        bf16x8 a0l = *(const bf16x8*)&Al[swq(mw + jc, q)];
        bf16x8 b0h = *(const bf16x8*)&Bh[swq(nw + jc, q)];
        bf16x8 b0l = *(const bf16x8*)&Bl[swq(nw + jc, q)];
        bf16x8 b1h = *(const bf16x8*)&Bh[swq(nw + 16 + jc, q)];
        bf16x8 b1l = *(const bf16x8*)&Bl[swq(nw + 16 + jc, q)];
        acc[0] = __builtin_amdgcn_mfma_f32_16x16x32_bf16(a0h, b0h, acc[0], 0, 0, 0);
        acc[0] = __builtin_amdgcn_mfma_f32_16x16x32_bf16(a0h, b0l, acc[0], 0, 0, 0);
        acc[0] = __builtin_amdgcn_mfma_f32_16x16x32_bf16(a0l, b0h, acc[0], 0, 0, 0);
        acc[1] = __builtin_amdgcn_mfma_f32_16x16x32_bf16(a0h, b1h, acc[1], 0, 0, 0);
        acc[1] = __builtin_amdgcn_mfma_f32_16x16x32_bf16(a0h, b1l, acc[1], 0, 0, 0);
        acc[1] = __builtin_amdgcn_mfma_f32_16x16x32_bf16(a0l, b1h, acc[1], 0, 0, 0);
      }
      __syncthreads();
    }
    const int sec = n0 >> 9;
    const int hh_ = (n0 >> 6) & 7;
    if (sec < 2) {
      unsigned short* dh = (sec == 0) ? qhi : khi;
      unsigned short* dl = (sec == 0) ? qlo : klo;
      const float scl = (sec == 0) ? 0.125f : 1.0f;
      #pragma unroll
      for (int j = 0; j < 2; ++j)
        #pragma unroll
        for (int r = 0; r < 4; ++r) {
          int tok = m0 + mw + blk * 4 + r;
          int b = tok >> 9, nn = tok & 511;
          int d = nw + j * 16 + jc;
          unsigned short h, l;
          split2(acc[j][r] * scl, h, l);
          int addr = ((b * 8 + hh_) * 512 + nn) * 64 + d;
          dh[addr] = h;
          dl[addr] = l;
        }
    } else {
      float* T = (float*)SM;             // [64 d][68 tok] fp32 = 17408 B
      #pragma unroll
      for (int j = 0; j < 2; ++j)
        #pragma unroll
        for (int r = 0; r < 4; ++r)
          T[(nw + j * 16 + jc) * 68 + mw + blk * 4 + r] = acc[j][r];
      __syncthreads();
      const int d = t >> 3, tq = (t & 7) * 8;
      const int b = m0 >> 9, nb = m0 & 511;
      #pragma unroll
      for (int c = 0; c < 2; ++c) {
        float4 vv = *(float4*)&T[d * 68 + tq + c * 4];
        ushort4 hv, lv;
        split2(vv.x, hv.x, lv.x); split2(vv.y, hv.y, lv.y);
        split2(vv.z, hv.z, lv.z); split2(vv.w, hv.w, lv.w);
        int addr = ((b * 8 + hh_) * 64 + d) * 512 + nb + tq + c * 4;
        *(ushort4*)&vthi[addr] = hv;
        *(ushort4*)&vtlo[addr] = lv;
      }
    }
    return;
  }

  // ---- RPE bias path: one pair per thread -------------------------------
  const int gid = (bid - 384) * 512 + t;   // < 524288
  const int b = gid >> 18;
  const int i = (gid >> 9) & 511;
  const int j = gid & 511;
  const float pix = pos[(b * 512 + i) * 2 + 0];
  const float piy = pos[(b * 512 + i) * 2 + 1];
  const float pjx = pos[(b * 512 + j) * 2 + 0];
  const float pjy = pos[(b * 512 + j) * 2 + 1];
  float txv = (pjx - pix) * 0.1f; float ux = txv / (1.0f + fabsf(txv));
  float tyv = (pjy - piy) * 0.1f; float uy = tyv / (1.0f + fabsf(tyv));
  const float invstep = (float)(TBL - 1) / (2.0f * UMAXV);
  float fx = (ux + UMAXV) * invstep;
  int ix = (int)fx; ix = min(max(ix, 0), TBL - 2);
  float wx = fx - (float)ix;
  float fy = (uy + UMAXV) * invstep;
  int iy = (int)fy; iy = min(max(iy, 0), TBL - 2);
  float wy = fy - (float)iy;

  __half hx0[16], hx1[16], hy0[16], hy1[16];
  *(uint4*)&hx0[0] = *(const uint4*)&Tx[ix * 16];
  *(uint4*)&hx0[8] = *(const uint4*)&Tx[ix * 16 + 8];
  *(uint4*)&hx1[0] = *(const uint4*)&Tx[(ix + 1) * 16];
  *(uint4*)&hx1[8] = *(const uint4*)&Tx[(ix + 1) * 16 + 8];
  *(uint4*)&hy0[0] = *(const uint4*)&Ty[iy * 16];
  *(uint4*)&hy0[8] = *(const uint4*)&Ty[iy * 16 + 8];
  *(uint4*)&hy1[0] = *(const uint4*)&Ty[(iy + 1) * 16];
  *(uint4*)&hy1[8] = *(const uint4*)&Ty[(iy + 1) * 16 + 8];

  float o[8];
  #pragma unroll
  for (int c = 0; c < 8; ++c) o[c] = b2[c];
  #pragma unroll
  for (int r = 0; r < 16; ++r) {
    float ax = __half2float(hx0[r]);
    float bx = __half2float(hx1[r]);
    float ay = __half2float(hy0[r]);
    float by = __half2float(hy1[r]);
    float hv = fmaf(wx, bx - ax, ax) + fmaf(wy, by - ay, ay);
    float z = hv * 0.70710678118654752f;
    float az = fabsf(z);
    float tt = __builtin_amdgcn_rcpf(fmaf(0.3275911f, az, 1.0f));
    float poly = ((((1.061405429f * tt - 1.453152027f) * tt + 1.421413741f) * tt
                   - 0.284496736f) * tt + 0.254829592f) * tt;
    float ex = __expf(-z * z);
    float erfv = copysignf(fmaf(-poly, ex, 1.0f), z);
    float g = 0.5f * hv * (1.0f + erfv);
    #pragma unroll
    for (int c = 0; c < 8; ++c)
      o[c] = fmaf(g, W2[r * 8 + c], o[c]);
  }
  #pragma unroll
  for (int c = 0; c < 8; ++c)
    bias[((b * 8 + c) * 512 + i) * 512 + j] = f2bf(o[c]);
}

// ---------------- K3: MFMA flash attention ----------------------------------
// grid 512 = (b, h, 16-row i-tile); 8 waves, wave w owns j in [w*64, w*64+64)
__global__ __launch_bounds__(512) void k_attn(
    const unsigned short* __restrict__ qhi, const unsigned short* __restrict__ qlo,
    const unsigned short* __restrict__ khi, const unsigned short* __restrict__ klo,
    const unsigned short* __restrict__ vthi, const unsigned short* __restrict__ vtlo,
    const unsigned short* __restrict__ bias,
    unsigned short* __restrict__ aoh, unsigned short* __restrict__ aol) {
  __shared__ __align__(16) unsigned short psu[8 * 512];
  __shared__ __align__(16) float olds[8 * 16 * 65];   // aliased: bstage[16][520] bf16
  __shared__ float mls[8 * 16 * 2];
  unsigned short* bst = (unsigned short*)olds;

  const int bid = blockIdx.x;
  const int it = bid & 31, h = (bid >> 5) & 7, b = bid >> 8;
  const int i0 = it * 16;
  const int bh = b * 8 + h;
  const int tid = threadIdx.x;
  const int w = tid >> 6, lane = tid & 63;
  const int blk = lane >> 4, jc = lane & 15;

  // stage the 16x512 bias slice into LDS (rows padded to 520)
  {
    const unsigned short* bgp = bias + ((size_t)(bh * 512 + i0)) * 512;
    int brow = tid >> 5, bc = (tid & 31) * 16;
    *(bf16x8*)&bst[brow * 520 + bc]     = *(const bf16x8*)&bgp[brow * 512 + bc];
    *(bf16x8*)&bst[brow * 520 + bc + 8] = *(const bf16x8*)&bgp[brow * 512 + bc + 8];
  }

  const int qoff = (bh * 512 + i0 + jc) * 64 + blk * 8;
  const bf16x8 qa0h = *(const bf16x8*)&qhi[qoff];
  const bf16x8 qa1h = *(const bf16x8*)&qhi[qoff + 32];
  const bf16x8 qa0l = *(const bf16x8*)&qlo[qoff];
  const bf16x8 qa1l = *(const bf16x8*)&qlo[qoff + 32];

  float m[4] = {-1e30f, -1e30f, -1e30f, -1e30f};
  float l[4] = {0.f, 0.f, 0.f, 0.f};
  f32x4 o[4];
  #pragma unroll
  for (int dt = 0; dt < 4; ++dt) o[dt] = f32x4{0.f, 0.f, 0.f, 0.f};

  unsigned short* pw = &psu[w * 512];
  __syncthreads();   // bias staged

  #pragma unroll
  for (int jt = 0; jt < 2; ++jt) {
    const int j0 = w * 64 + jt * 32;
    const int rA = (bh * 512 + j0 + jc) * 64 + blk * 8;
    const int rB = rA + 16 * 64;
    bf16x8 kA0h = *(const bf16x8*)&khi[rA];
    bf16x8 kA1h = *(const bf16x8*)&khi[rA + 32];
    bf16x8 kA0l = *(const bf16x8*)&klo[rA];
    bf16x8 kA1l = *(const bf16x8*)&klo[rA + 32];
    bf16x8 kB0h = *(const bf16x8*)&khi[rB];
    bf16x8 kB1h = *(const bf16x8*)&khi[rB + 32];
    bf16x8 kB0l = *(const bf16x8*)&klo[rB];
    bf16x8 kB1l = *(const bf16x8*)&klo[rB + 32];

    f32x4 aA = {0.f, 0.f, 0.f, 0.f};
    aA = __builtin_amdgcn_mfma_f32_16x16x32_bf16(qa0h, kA0h, aA, 0, 0, 0);
    aA = __builtin_amdgcn_mfma_f32_16x16x32_bf16(qa0h, kA0l, aA, 0, 0, 0);
    aA = __builtin_amdgcn_mfma_f32_16x16x32_bf16(qa0l, kA0h, aA, 0, 0, 0);
    aA = __builtin_amdgcn_mfma_f32_16x16x32_bf16(qa1h, kA1h, aA, 0, 0, 0);
    aA = __builtin_amdgcn_mfma_f32_16x16x32_bf16(qa1h, kA1l, aA, 0, 0, 0);
    aA = __builtin_amdgcn_mfma_f32_16x16x32_bf16(qa1l, kA1h, aA, 0, 0, 0);
    f32x4 aB = {0.f, 0.f, 0.f, 0.f};
    aB = __builtin_amdgcn_mfma_f32_16x16x32_bf16(qa0h, kB0h, aB, 0, 0, 0);
    aB = __builtin_amdgcn_mfma_f32_16x16x32_bf16(qa0h, kB0l, aB, 0, 0, 0);
    aB = __builtin_amdgcn_mfma_f32_16x16x32_bf16(qa0l, kB0h, aB, 0, 0, 0);
    aB = __builtin_amdgcn_mfma_f32_16x16x32_bf16(qa1h, kB1h, aB, 0, 0, 0);
    aB = __builtin_amdgcn_mfma_f32_16x16x32_bf16(qa1h, kB1l, aB, 0, 0, 0);
    aB = __builtin_amdgcn_mfma_f32_16x16x32_bf16(qa1l, kB1h, aB, 0, 0, 0);

    float sA[4], sB[4], sc[4];
    #pragma unroll
    for (int r = 0; r < 4; ++r) {
      const int br = (blk * 4 + r) * 520;
      sA[r] = aA[r] + bf2f(bst[br + j0 + jc]);
      sB[r] = aB[r] + bf2f(bst[br + j0 + 16 + jc]);
    }
    #pragma unroll
    for (int r = 0; r < 4; ++r) {
      float mx = fmaxf(sA[r], sB[r]);
      mx = fmaxf(mx, __shfl_xor(mx, 1, 64));
      mx = fmaxf(mx, __shfl_xor(mx, 2, 64));
      mx = fmaxf(mx, __shfl_xor(mx, 4, 64));
      mx = fmaxf(mx, __shfl_xor(mx, 8, 64));
      float mn = fmaxf(m[r], mx);
      sc[r] = __expf(m[r] - mn);
      m[r] = mn;
      float pA = __expf(sA[r] - mn);
      float pB = __expf(sB[r] - mn);
      float ps = pA + pB;
      ps += __shfl_xor(ps, 1, 64);
      ps += __shfl_xor(ps, 2, 64);
      ps += __shfl_xor(ps, 4, 64);
      ps += __shfl_xor(ps, 8, 64);
      l[r] = l[r] * sc[r] + ps;
      pw[(blk * 4 + r) * 32 + jc] = f2bf(pA);
      pw[(blk * 4 + r) * 32 + 16 + jc] = f2bf(pB);
    }
    #pragma unroll
    for (int dt = 0; dt < 4; ++dt)
      #pragma unroll
      for (int r = 0; r < 4; ++r)
        o[dt][r] *= sc[r];
    bf16x8 pf = *(const bf16x8*)&pw[jc * 32 + blk * 8];
    #pragma unroll
    for (int dt = 0; dt < 4; ++dt) {
      const int va = (bh * 64 + dt * 16 + jc) * 512 + j0 + blk * 8;
      bf16x8 vh = *(const bf16x8*)&vthi[va];
      bf16x8 vl = *(const bf16x8*)&vtlo[va];
      o[dt] = __builtin_amdgcn_mfma_f32_16x16x32_bf16(pf, vh, o[dt], 0, 0, 0);
      o[dt] = __builtin_amdgcn_mfma_f32_16x16x32_bf16(pf, vl, o[dt], 0, 0, 0);
    }
  }
  __syncthreads();   // all waves done with bstage before olds overwrite
  #pragma unroll
  for (int dt = 0; dt < 4; ++dt)
    #pragma unroll
    for (int r = 0; r < 4; ++r)
      olds[(w * 16 + blk * 4 + r) * 65 + dt * 16 + jc] = o[dt][r];
  if (jc == 0) {
    #pragma unroll
    for (int r = 0; r < 4; ++r) {
      mls[(w * 16 + blk * 4 + r) * 2 + 0] = m[r];
      mls[(w * 16 + blk * 4 + r) * 2 + 1] = l[r];
    }
  }
  __syncthreads();
  #pragma unroll
  for (int itx = 0; itx < 2; ++itx) {
    int idx = tid + itx * 512;
    int q = idx >> 6, d = idx & 63;
    float M = -1e30f;
    #pragma unroll
    for (int ww = 0; ww < 8; ++ww) M = fmaxf(M, mls[(ww * 16 + q) * 2]);
    float L = 0.f, acc = 0.f;
    #pragma unroll
    for (int ww = 0; ww < 8; ++ww) {
      float e = __expf(mls[(ww * 16 + q) * 2] - M);
      L += mls[(ww * 16 + q) * 2 + 1] * e;
      acc += olds[(ww * 16 + q) * 65 + d] * e;
    }
    unsigned short oh, ol;
    split2(acc / L, oh, ol);
    int addr = (b * 512 + i0 + q) * 512 + h * 64 + d;
    aoh[addr] = oh;
    aol[addr] = ol;
  }
}

// ---------------- K4: output GEMM via MFMA  out = ao @ Wout + bout ----------
__global__ __launch_bounds__(256) void k_out(
    const unsigned short* __restrict__ aoh, const unsigned short* __restrict__ aol,
    const unsigned short* __restrict__ Wh, const unsigned short* __restrict__ Wl,
    const float* __restrict__ bout, float* __restrict__ out) {
  __shared__ __align__(16) unsigned short SM[12288];   // 24 KB
  unsigned short* Ah = SM;                             // [32][64]
  unsigned short* Al = SM + 2048;
  unsigned short* Bh = SM + 4096;                      // [64][64]
  unsigned short* Bl = SM + 8192;

  const int bid = blockIdx.x;            // 32*8
  const int mt = bid >> 3, nt = bid & 7;
  const int m0 = mt * 32, n0 = nt * 64;
  const int t = threadIdx.x;
  const int w = t >> 6, lane = t & 63, blk = lane >> 4, jc = lane & 15;
  const int mh_ = (w & 1) * 16, nh_ = (w >> 1) * 32;
  const int sm = t >> 3, sq = t & 7;     // sm: 0..31

  f32x4 acc[2];
  acc[0] = f32x4{0.f, 0.f, 0.f, 0.f};
  acc[1] = f32x4{0.f, 0.f, 0.f, 0.f};

  bf16x8 pa, pal, pb[2], pbl[2];
  {
    int off = (m0 + sm) * 512 + sq * 8;
    pa  = *(const bf16x8*)&aoh[off];
    pal = *(const bf16x8*)&aol[off];
    #pragma unroll
    for (int c = 0; c < 2; ++c) {
      int ofb = (n0 + sm + c * 32) * 512 + sq * 8;
      pb[c]  = *(const bf16x8*)&Wh[ofb];
      pbl[c] = *(const bf16x8*)&Wl[ofb];
    }
  }
  for (int it = 0; it < 8; ++it) {
    {
      int a = swq(sm, sq);
      *(bf16x8*)&Ah[a] = pa;
      *(bf16x8*)&Al[a] = pal;
      #pragma unroll
      for (int c = 0; c < 2; ++c) {
        int bca = swq(sm + c * 32, sq);
        *(bf16x8*)&Bh[bca] = pb[c];
        *(bf16x8*)&Bl[bca] = pbl[c];
      }
    }
    __syncthreads();
    if (it < 7) {
      int k0 = (it + 1) * 64;
      int off = (m0 + sm) * 512 + k0 + sq * 8;
      pa  = *(const bf16x8*)&aoh[off];
      pal = *(const bf16x8*)&aol[off];
      #pragma unroll
      for (int c = 0; c < 2; ++c) {
        int ofb = (n0 + sm + c * 32) * 512 + k0 + sq * 8;
        pb[c]  = *(const bf16x8*)&Wh[ofb];
        pbl[c] = *(const bf16x8*)&Wl[ofb];
      }
    }
    #pragma unroll
    for (int h = 0; h < 2; ++h) {
      int q = h * 4 + blk;
      bf16x8 a0h = *(const bf16x8*)&Ah[swq(mh_ + jc, q)];
      bf16x8 a0l = *(const bf16x8*)&Al[swq(mh_ + jc, q)];
      bf16x8 b0h = *(const bf16x8*)&Bh[swq(nh_ + jc, q)];
      bf16x8 b0l = *(const bf16x8*)&Bl[swq(nh_ + jc, q)];
      bf16x8 b1h = *(const bf16x8*)&Bh[swq(nh_ + 16 + jc, q)];
      bf16x8 b1l = *(const bf16x8*)&Bl[swq(nh_ + 16 + jc, q)];
      acc[0] = __builtin_amdgcn_mfma_f32_16x16x32_bf16(a0h, b0h, acc[0], 0, 0, 0);
      acc[0] = __builtin_amdgcn_mfma_f32_16x16x32_bf16(a0h, b0l, acc[0], 0, 0, 0);
      acc[0] = __builtin_amdgcn_mfma_f32_16x16x32_bf16(a0l, b0h, acc[0], 0, 0, 0);
      acc[1] = __builtin_amdgcn_mfma_f32_16x16x32_bf16(a0h, b1h, acc[1], 0, 0, 0);
      acc[1] = __builtin_amdgcn_mfma_f32_16x16x32_bf16(a0h, b1l, acc[1], 0, 0, 0);
      acc[1] = __builtin_amdgcn_mfma_f32_16x16x32_bf16(a0l, b1h, acc[1], 0, 0, 0);
    }
    __syncthreads();
  }
  #pragma unroll
  for (int j = 0; j < 2; ++j) {
    int n = n0 + nh_ + j * 16 + jc;
    float bb = bout[n];
    #pragma unroll
    for (int r = 0; r < 4; ++r) {
      int row = m0 + mh_ + blk * 4 + r;
      out[row * 512 + n] = acc[j][r] + bb;
    }
  }
}

extern "C" void kernel_launch(void* const* d_in, const int* in_sizes, int n_in,
                              void* d_out, int out_size, void* d_ws, size_t ws_size,
                              hipStream_t stream) {
  const float* x    = (const float*)d_in[0];
  const float* pos  = (const float*)d_in[1];
  const float* Wqkv = (const float*)d_in[2];
  const float* Wout = (const float*)d_in[3];
  const float* bout = (const float*)d_in[4];
  const float* W1   = (const float*)d_in[5];
  const float* b1   = (const float*)d_in[6];
  const float* W2   = (const float*)d_in[7];
  const float* b2   = (const float*)d_in[8];
  float* out = (float*)d_out;
  char* base = (char*)d_ws;

  __half* Tx = (__half*)(base);                                // 16 KB used
  __half* Ty = (__half*)(base + 32768);                        // 16 KB used
  unsigned short* xh   = (unsigned short*)(base + 65536);      // 1 MB
  unsigned short* xl   = (unsigned short*)(base + 1114112);    // 1 MB
  unsigned short* Wth  = (unsigned short*)(base + 2162688);    // 1.5 MB
  unsigned short* Wtl  = (unsigned short*)(base + 3735552);    // 1.5 MB
  unsigned short* Woth = (unsigned short*)(base + 5308416);    // 512 KB
  unsigned short* Wotl = (unsigned short*)(base + 5832704);    // 512 KB
  unsigned short* qhi  = (unsigned short*)(base + 6356992);    // 1 MB
  unsigned short* qlo  = (unsigned short*)(base + 7405568);
  unsigned short* khi  = (unsigned short*)(base + 8454144);
  unsigned short* klo  = (unsigned short*)(base + 9502720);
  unsigned short* vthi = (unsigned short*)(base + 10551296);
  unsigned short* vtlo = (unsigned short*)(base + 11599872);
  unsigned short* bias = (unsigned short*)(base + 12648448);   // 8 MB
  unsigned short* aoh  = (unsigned short*)(base + 21037056);   // 1 MB
  unsigned short* aol  = (unsigned short*)(base + 22085632);   // 1 MB

  hipLaunchKernelGGL(k_prep, dim3(1600), dim3(256), 0, stream,
                     x, Wqkv, Wout, W1, b1, xh, xl, Wth, Wtl, Woth, Wotl, Tx, Ty);
  hipLaunchKernelGGL(k_fused, dim3(1408), dim3(512), 0, stream,
                     xh, xl, Wth, Wtl, qhi, qlo, khi, klo, vthi, vtlo,
                     pos, Tx, Ty, W2, b2, bias);
  hipLaunchKernelGGL(k_attn, dim3(512), dim3(512), 0, stream,
                     qhi, qlo, khi, klo, vthi, vtlo, bias, aoh, aol);
  hipLaunchKernelGGL(k_out,  dim3(256), dim3(256), 0, stream,
                     aoh, aol, Woth, Wotl, bout, out);
}

// Round 5
// 43.969 us; speedup vs baseline: 3.7930x; 1.2286x over previous
//
#include <hip/hip_runtime.h>
#include <hip/hip_fp16.h>
#include <math.h>

typedef __attribute__((ext_vector_type(8))) _Float16 f16x8;
typedef __attribute__((ext_vector_type(4))) float f32x4;

#define TBL 512
#define UMAXV (1.0f/11.0f)

// swizzled 16B-quad element index within a [rows][64-f16] LDS tile
__device__ __forceinline__ int swq(int row, int q) {
  return row * 64 + ((q ^ (row & 7)) << 3);
}
__device__ __forceinline__ f16x8 cvt8(float4 a, float4 b) {
  f16x8 r;
  r[0] = (_Float16)a.x; r[1] = (_Float16)a.y;
  r[2] = (_Float16)a.z; r[3] = (_Float16)a.w;
  r[4] = (_Float16)b.x; r[5] = (_Float16)b.y;
  r[6] = (_Float16)b.z; r[7] = (_Float16)b.w;
  return r;
}

// ---------------- K_prep: transpose+cvt Wqkv/Wout to fp16; build tables -----
__global__ __launch_bounds__(256) void k_prep(
    const float* __restrict__ Wqkv, const float* __restrict__ Wout,
    const float* __restrict__ W1, const float* __restrict__ b1,
    _Float16* __restrict__ Wt, _Float16* __restrict__ Wot,
    __half* __restrict__ Tx, __half* __restrict__ Ty) {
  __shared__ float Tt[32 * 33];
  const int t = threadIdx.x;
  const int bid = blockIdx.x;
  if (bid >= 1024) {                     // hidden-layer tables
    int gid = (bid - 1024) * 256 + t;
    int e = gid >> 5, c = gid & 31;
    float u = -UMAXV + (2.0f * UMAXV) * (float)e / (float)(TBL - 1);
    const int xpart = (c < 16);
    const int col = c & 15;
    const int base = xpart ? 0 : 65;
    float sum = u * W1[base * 16 + col] + (xpart ? b1[col] : 0.0f);
    float s1, c1;
    sincosf(u * 3.14159265358979323846f, &s1, &c1);
    float sk = s1, ck = c1;
    for (int k = 1; k <= 32; ++k) {
      sum += sk * W1[(base + k) * 16 + col] + ck * W1[(base + 32 + k) * 16 + col];
      float ns = sk * c1 + ck * s1;
      ck = ck * c1 - sk * s1;
      sk = ns;
    }
    (xpart ? Tx : Ty)[e * 16 + col] = __float2half(sum);
    return;
  }
  int k0, n0, ncols;
  const float* W;
  _Float16* O;
  if (bid < 768) {                       // Wqkv: 512x1536 -> Wt[1536][512]
    k0 = (bid / 48) * 32; n0 = (bid % 48) * 32; ncols = 1536;
    W = Wqkv; O = Wt;
  } else {                               // Wout: 512x512 -> Wot[512][512]
    int tile = bid - 768;
    k0 = (tile / 16) * 32; n0 = (tile % 16) * 32; ncols = 512;
    W = Wout; O = Wot;
  }
  {
    int kl = t >> 3, nl = (t & 7) * 4;
    float4 v = *(const float4*)&W[(k0 + kl) * ncols + n0 + nl];
    Tt[kl * 33 + nl + 0] = v.x;
    Tt[kl * 33 + nl + 1] = v.y;
    Tt[kl * 33 + nl + 2] = v.z;
    Tt[kl * 33 + nl + 3] = v.w;
  }
  __syncthreads();
  {
    int nl = t >> 3, kq = (t & 7) * 4;
    ushort4 h;
    h.x = __builtin_bit_cast(unsigned short, (_Float16)Tt[(kq + 0) * 33 + nl]);
    h.y = __builtin_bit_cast(unsigned short, (_Float16)Tt[(kq + 1) * 33 + nl]);
    h.z = __builtin_bit_cast(unsigned short, (_Float16)Tt[(kq + 2) * 33 + nl]);
    h.w = __builtin_bit_cast(unsigned short, (_Float16)Tt[(kq + 3) * 33 + nl]);
    *(ushort4*)&O[(n0 + nl) * 512 + k0 + kq] = h;
  }
}

// ---------------- K_fused: QKV MFMA GEMM (bid<192) + RPE bias (bid>=192) ----
__global__ __launch_bounds__(512) void k_fused(
    const float* __restrict__ x, const _Float16* __restrict__ Wt,
    _Float16* __restrict__ q16, _Float16* __restrict__ k16,
    _Float16* __restrict__ vt16,
    const float* __restrict__ pos,
    const __half* __restrict__ Tx, const __half* __restrict__ Ty,
    const float* __restrict__ W2, const float* __restrict__ b2,
    _Float16* __restrict__ bias) {
  __shared__ __align__(16) unsigned short SM[16384];   // 32 KB (qkv path only)
  const int bid = blockIdx.x;
  const int t = threadIdx.x;

  if (bid < 192) {
    // ---- QKV GEMM: 128x64 tile, 8 waves (32x32 per wave), K=512 -----------
    _Float16* Ah = (_Float16*)SM;            // [128][64] = 16 KB
    _Float16* Bh = (_Float16*)SM + 8192;     // [64][64]  = 8 KB
    const int mt = bid / 24, nt = bid % 24;
    const int m0 = mt * 128, n0 = nt * 64;
    const int w = t >> 6, lane = t & 63, blk = lane >> 4, jc = lane & 15;
    const int mw = (w & 3) * 32, nw = (w >> 2) * 32;
    const int sa = t >> 3, sq = t & 7;

    f32x4 acc[2][2];
    #pragma unroll
    for (int i = 0; i < 2; ++i)
      #pragma unroll
      for (int j = 0; j < 2; ++j) acc[i][j] = f32x4{0.f, 0.f, 0.f, 0.f};

    float4 pax[2][2];
    f16x8 pbv;
    #pragma unroll
    for (int c = 0; c < 2; ++c) {
      const float* xp = &x[(m0 + sa + c * 64) * 512 + sq * 8];
      pax[c][0] = *(const float4*)xp;
      pax[c][1] = *(const float4*)(xp + 4);
    }
    pbv = *(const f16x8*)&Wt[(n0 + sa) * 512 + sq * 8];

    for (int it = 0; it < 8; ++it) {
      #pragma unroll
      for (int c = 0; c < 2; ++c)
        *(f16x8*)&Ah[swq(sa + c * 64, sq)] = cvt8(pax[c][0], pax[c][1]);
      *(f16x8*)&Bh[swq(sa, sq)] = pbv;
      __syncthreads();
      if (it < 7) {
        int k0 = (it + 1) * 64;
        #pragma unroll
        for (int c = 0; c < 2; ++c) {
          const float* xp = &x[(m0 + sa + c * 64) * 512 + k0 + sq * 8];
          pax[c][0] = *(const float4*)xp;
          pax[c][1] = *(const float4*)(xp + 4);
        }
        pbv = *(const f16x8*)&Wt[(n0 + sa) * 512 + k0 + sq * 8];
      }
      #pragma unroll
      for (int h = 0; h < 2; ++h) {
        int q = h * 4 + blk;
        f16x8 a0 = *(const f16x8*)&Ah[swq(mw + jc, q)];
        f16x8 a1 = *(const f16x8*)&Ah[swq(mw + 16 + jc, q)];
        f16x8 b0 = *(const f16x8*)&Bh[swq(nw + jc, q)];
        f16x8 b1 = *(const f16x8*)&Bh[swq(nw + 16 + jc, q)];
        acc[0][0] = __builtin_amdgcn_mfma_f32_16x16x32_f16(a0, b0, acc[0][0], 0, 0, 0);
        acc[0][1] = __builtin_amdgcn_mfma_f32_16x16x32_f16(a0, b1, acc[0][1], 0, 0, 0);
        acc[1][0] = __builtin_amdgcn_mfma_f32_16x16x32_f16(a1, b0, acc[1][0], 0, 0, 0);
        acc[1][1] = __builtin_amdgcn_mfma_f32_16x16x32_f16(a1, b1, acc[1][1], 0, 0, 0);
      }
      __syncthreads();
    }
    const int sec = n0 >> 9;
    const int hh_ = (n0 >> 6) & 7;
    if (sec < 2) {
      _Float16* dst = (sec == 0) ? q16 : k16;
      const float scl = (sec == 0) ? 0.125f : 1.0f;
      #pragma unroll
      for (int i = 0; i < 2; ++i)
        #pragma unroll
        for (int j = 0; j < 2; ++j)
          #pragma unroll
          for (int r = 0; r < 4; ++r) {
            int tok = m0 + mw + i * 16 + blk * 4 + r;
            int b = tok >> 9, nn = tok & 511;
            int d = nw + j * 16 + jc;
            dst[((b * 8 + hh_) * 512 + nn) * 64 + d] = (_Float16)(acc[i][j][r] * scl);
          }
    } else {
      _Float16* T = (_Float16*)SM;       // [64 d][136 tok pad] = 17408 B
      #pragma unroll
      for (int i = 0; i < 2; ++i)
        #pragma unroll
        for (int j = 0; j < 2; ++j)
          #pragma unroll
          for (int r = 0; r < 4; ++r)
            T[(nw + j * 16 + jc) * 136 + mw + i * 16 + blk * 4 + r] =
                (_Float16)acc[i][j][r];
      __syncthreads();
      const int d = t >> 3, tq = t & 7;
      const int b = m0 >> 9, nb = m0 & 511;
      #pragma unroll
      for (int c = 0; c < 2; ++c) {
        int qd = tq + c * 8;
        f16x8 vv = *(const f16x8*)&T[d * 136 + qd * 8];
        *(f16x8*)&vt16[((b * 8 + hh_) * 64 + d) * 512 + nb + qd * 8] = vv;
      }
    }
    return;
  }

  // ---- RPE bias path: one pair per thread --------------------------------
  const int gid = (bid - 192) * 512 + t;   // < 524288
  const int b = gid >> 18;
  const int i = (gid >> 9) & 511;
  const int j = gid & 511;
  const float pix = pos[(b * 512 + i) * 2 + 0];
  const float piy = pos[(b * 512 + i) * 2 + 1];
  const float pjx = pos[(b * 512 + j) * 2 + 0];
  const float pjy = pos[(b * 512 + j) * 2 + 1];
  float txv = (pjx - pix) * 0.1f; float ux = txv / (1.0f + fabsf(txv));
  float tyv = (pjy - piy) * 0.1f; float uy = tyv / (1.0f + fabsf(tyv));
  const float invstep = (float)(TBL - 1) / (2.0f * UMAXV);
  float fx = (ux + UMAXV) * invstep;
  int ix = (int)fx; ix = min(max(ix, 0), TBL - 2);
  float wx = fx - (float)ix;
  float fy = (uy + UMAXV) * invstep;
  int iy = (int)fy; iy = min(max(iy, 0), TBL - 2);
  float wy = fy - (float)iy;

  __half hx0[16], hx1[16], hy0[16], hy1[16];
  *(uint4*)&hx0[0] = *(const uint4*)&Tx[ix * 16];
  *(uint4*)&hx0[8] = *(const uint4*)&Tx[ix * 16 + 8];
  *(uint4*)&hx1[0] = *(const uint4*)&Tx[(ix + 1) * 16];
  *(uint4*)&hx1[8] = *(const uint4*)&Tx[(ix + 1) * 16 + 8];
  *(uint4*)&hy0[0] = *(const uint4*)&Ty[iy * 16];
  *(uint4*)&hy0[8] = *(const uint4*)&Ty[iy * 16 + 8];
  *(uint4*)&hy1[0] = *(const uint4*)&Ty[(iy + 1) * 16];
  *(uint4*)&hy1[8] = *(const uint4*)&Ty[(iy + 1) * 16 + 8];

  float o[8];
  #pragma unroll
  for (int c = 0; c < 8; ++c) o[c] = b2[c];
  #pragma unroll
  for (int r = 0; r < 16; ++r) {
    float ax = __half2float(hx0[r]);
    float bx = __half2float(hx1[r]);
    float ay = __half2float(hy0[r]);
    float by = __half2float(hy1[r]);
    float hv = fmaf(wx, bx - ax, ax) + fmaf(wy, by - ay, ay);
    float z = hv * 0.70710678118654752f;
    float az = fabsf(z);
    float tt = __builtin_amdgcn_rcpf(fmaf(0.3275911f, az, 1.0f));
    float poly = ((((1.061405429f * tt - 1.453152027f) * tt + 1.421413741f) * tt
                   - 0.284496736f) * tt + 0.254829592f) * tt;
    float ex = __expf(-z * z);
    float erfv = copysignf(fmaf(-poly, ex, 1.0f), z);
    float g = 0.5f * hv * (1.0f + erfv);
    #pragma unroll
    for (int c = 0; c < 8; ++c)
      o[c] = fmaf(g, W2[r * 8 + c], o[c]);
  }
  #pragma unroll
  for (int c = 0; c < 8; ++c)
    bias[((size_t)(b * 8 + c) * 512 + i) * 512 + j] = (_Float16)o[c];
}

// ---------------- K3: MFMA flash attention (fp16) ---------------------------
// grid 512 = (b, h, 16-row i-tile); 8 waves, wave w owns j in [w*64, w*64+64)
__global__ __launch_bounds__(512) void k_attn(
    const _Float16* __restrict__ q16, const _Float16* __restrict__ k16,
    const _Float16* __restrict__ vt16, const _Float16* __restrict__ bias,
    _Float16* __restrict__ ao16) {
  __shared__ __align__(16) _Float16 psu[8 * 512];      // per-wave P [16][32]
  __shared__ __align__(16) float olds[8 * 16 * 65];    // aliased: bst[16][520] f16
  __shared__ float mls[8 * 16 * 2];
  _Float16* bst = (_Float16*)olds;

  const int bid = blockIdx.x;
  const int it = bid & 31, h = (bid >> 5) & 7, b = bid >> 8;
  const int i0 = it * 16;
  const int bh = b * 8 + h;
  const int tid = threadIdx.x;
  const int w = tid >> 6, lane = tid & 63;
  const int blk = lane >> 4, jc = lane & 15;

  // stage the 16x512 bias slice into LDS (rows padded to 520)
  {
    const _Float16* bgp = bias + ((size_t)(bh * 512 + i0)) * 512;
    int brow = tid >> 5, bc = (tid & 31) * 16;
    *(f16x8*)&bst[brow * 520 + bc]     = *(const f16x8*)&bgp[brow * 512 + bc];
    *(f16x8*)&bst[brow * 520 + bc + 8] = *(const f16x8*)&bgp[brow * 512 + bc + 8];
  }

  const int qoff = (bh * 512 + i0 + jc) * 64 + blk * 8;
  const f16x8 qa0 = *(const f16x8*)&q16[qoff];
  const f16x8 qa1 = *(const f16x8*)&q16[qoff + 32];

  float m[4] = {-1e30f, -1e30f, -1e30f, -1e30f};
  float l[4] = {0.f, 0.f, 0.f, 0.f};
  f32x4 o[4];
  #pragma unroll
  for (int dt = 0; dt < 4; ++dt) o[dt] = f32x4{0.f, 0.f, 0.f, 0.f};

  _Float16* pw = &psu[w * 512];
  __syncthreads();   // bias staged

  #pragma unroll
  for (int jt = 0; jt < 2; ++jt) {
    const int j0 = w * 64 + jt * 32;
    const int rA = (bh * 512 + j0 + jc) * 64 + blk * 8;
    const int rB = rA + 16 * 64;
    f16x8 kA0 = *(const f16x8*)&k16[rA];
    f16x8 kA1 = *(const f16x8*)&k16[rA + 32];
    f16x8 kB0 = *(const f16x8*)&k16[rB];
    f16x8 kB1 = *(const f16x8*)&k16[rB + 32];

    f32x4 aA = {0.f, 0.f, 0.f, 0.f};
    aA = __builtin_amdgcn_mfma_f32_16x16x32_f16(qa0, kA0, aA, 0, 0, 0);
    aA = __builtin_amdgcn_mfma_f32_16x16x32_f16(qa1, kA1, aA, 0, 0, 0);
    f32x4 aB = {0.f, 0.f, 0.f, 0.f};
    aB = __builtin_amdgcn_mfma_f32_16x16x32_f16(qa0, kB0, aB, 0, 0, 0);
    aB = __builtin_amdgcn_mfma_f32_16x16x32_f16(qa1, kB1, aB, 0, 0, 0);

    float sA[4], sB[4], sc[4];
    #pragma unroll
    for (int r = 0; r < 4; ++r) {
      const int br = (blk * 4 + r) * 520;
      sA[r] = aA[r] + (float)bst[br + j0 + jc];
      sB[r] = aB[r] + (float)bst[br + j0 + 16 + jc];
    }
    #pragma unroll
    for (int r = 0; r < 4; ++r) {
      float mx = fmaxf(sA[r], sB[r]);
      mx = fmaxf(mx, __shfl_xor(mx, 1, 64));
      mx = fmaxf(mx, __shfl_xor(mx, 2, 64));
      mx = fmaxf(mx, __shfl_xor(mx, 4, 64));
      mx = fmaxf(mx, __shfl_xor(mx, 8, 64));
      float mn = fmaxf(m[r], mx);
      sc[r] = __expf(m[r] - mn);
      m[r] = mn;
      float pA = __expf(sA[r] - mn);
      float pB = __expf(sB[r] - mn);
      float ps = pA + pB;
      ps += __shfl_xor(ps, 1, 64);
      ps += __shfl_xor(ps, 2, 64);
      ps += __shfl_xor(ps, 4, 64);
      ps += __shfl_xor(ps, 8, 64);
      l[r] = l[r] * sc[r] + ps;
      pw[(blk * 4 + r) * 32 + jc] = (_Float16)pA;
      pw[(blk * 4 + r) * 32 + 16 + jc] = (_Float16)pB;
    }
    #pragma unroll
    for (int dt = 0; dt < 4; ++dt)
      #pragma unroll
      for (int r = 0; r < 4; ++r)
        o[dt][r] *= sc[r];
    f16x8 pf = *(const f16x8*)&pw[jc * 32 + blk * 8];
    #pragma unroll
    for (int dt = 0; dt < 4; ++dt) {
      const int va = (bh * 64 + dt * 16 + jc) * 512 + j0 + blk * 8;
      f16x8 vh = *(const f16x8*)&vt16[va];
      o[dt] = __builtin_amdgcn_mfma_f32_16x16x32_f16(pf, vh, o[dt], 0, 0, 0);
    }
  }
  __syncthreads();   // all waves done with bst before olds overwrite
  #pragma unroll
  for (int dt = 0; dt < 4; ++dt)
    #pragma unroll
    for (int r = 0; r < 4; ++r)
      olds[(w * 16 + blk * 4 + r) * 65 + dt * 16 + jc] = o[dt][r];
  if (jc == 0) {
    #pragma unroll
    for (int r = 0; r < 4; ++r) {
      mls[(w * 16 + blk * 4 + r) * 2 + 0] = m[r];
      mls[(w * 16 + blk * 4 + r) * 2 + 1] = l[r];
    }
  }
  __syncthreads();
  #pragma unroll
  for (int itx = 0; itx < 2; ++itx) {
    int idx = tid + itx * 512;
    int q = idx >> 6, d = idx & 63;
    float M = -1e30f;
    #pragma unroll
    for (int ww = 0; ww < 8; ++ww) M = fmaxf(M, mls[(ww * 16 + q) * 2]);
    float L = 0.f, acc = 0.f;
    #pragma unroll
    for (int ww = 0; ww < 8; ++ww) {
      float e = __expf(mls[(ww * 16 + q) * 2] - M);
      L += mls[(ww * 16 + q) * 2 + 1] * e;
      acc += olds[(ww * 16 + q) * 65 + d] * e;
    }
    ao16[(b * 512 + i0 + q) * 512 + h * 64 + d] = (_Float16)(acc / L);
  }
}

// ---------------- K4: output GEMM via MFMA  out = ao @ Wout + bout ----------
__global__ __launch_bounds__(256) void k_out(
    const _Float16* __restrict__ ao16, const _Float16* __restrict__ Wot,
    const float* __restrict__ bout, float* __restrict__ out) {
  __shared__ __align__(16) unsigned short SM[6144];    // 12 KB
  _Float16* Ah = (_Float16*)SM;            // [32][64] 4 KB
  _Float16* Bh = (_Float16*)SM + 2048;     // [64][64] 8 KB

  const int bid = blockIdx.x;            // 32*8
  const int mt = bid >> 3, nt = bid & 7;
  const int m0 = mt * 32, n0 = nt * 64;
  const int t = threadIdx.x;
  const int w = t >> 6, lane = t & 63, blk = lane >> 4, jc = lane & 15;
  const int mh_ = (w & 1) * 16, nh_ = (w >> 1) * 32;
  const int sm = t >> 3, sq = t & 7;     // sm: 0..31

  f32x4 acc[2];
  acc[0] = f32x4{0.f, 0.f, 0.f, 0.f};
  acc[1] = f32x4{0.f, 0.f, 0.f, 0.f};

  f16x8 pa, pb[2];
  {
    pa = *(const f16x8*)&ao16[(m0 + sm) * 512 + sq * 8];
    #pragma unroll
    for (int c = 0; c < 2; ++c)
      pb[c] = *(const f16x8*)&Wot[(n0 + sm + c * 32) * 512 + sq * 8];
  }
  for (int it = 0; it < 8; ++it) {
    *(f16x8*)&Ah[swq(sm, sq)] = pa;
    #pragma unroll
    for (int c = 0; c < 2; ++c)
      *(f16x8*)&Bh[swq(sm + c * 32, sq)] = pb[c];
    __syncthreads();
    if (it < 7) {
      int k0 = (it + 1) * 64;
      pa = *(const f16x8*)&ao16[(m0 + sm) * 512 + k0 + sq * 8];
      #pragma unroll
      for (int c = 0; c < 2; ++c)
        pb[c] = *(const f16x8*)&Wot[(n0 + sm + c * 32) * 512 + k0 + sq * 8];
    }
    #pragma unroll
    for (int h = 0; h < 2; ++h) {
      int q = h * 4 + blk;
      f16x8 a0 = *(const f16x8*)&Ah[swq(mh_ + jc, q)];
      f16x8 b0 = *(const f16x8*)&Bh[swq(nh_ + jc, q)];
      f16x8 b1 = *(const f16x8*)&Bh[swq(nh_ + 16 + jc, q)];
      acc[0] = __builtin_amdgcn_mfma_f32_16x16x32_f16(a0, b0, acc[0], 0, 0, 0);
      acc[1] = __builtin_amdgcn_mfma_f32_16x16x32_f16(a0, b1, acc[1], 0, 0, 0);
    }
    __syncthreads();
  }
  #pragma unroll
  for (int j = 0; j < 2; ++j) {
    int n = n0 + nh_ + j * 16 + jc;
    float bb = bout[n];
    #pragma unroll
    for (int r = 0; r < 4; ++r) {
      int row = m0 + mh_ + blk * 4 + r;
      out[row * 512 + n] = acc[j][r] + bb;
    }
  }
}

extern "C" void kernel_launch(void* const* d_in, const int* in_sizes, int n_in,
                              void* d_out, int out_size, void* d_ws, size_t ws_size,
                              hipStream_t stream) {
  const float* x    = (const float*)d_in[0];
  const float* pos  = (const float*)d_in[1];
  const float* Wqkv = (const float*)d_in[2];
  const float* Wout = (const float*)d_in[3];
  const float* bout = (const float*)d_in[4];
  const float* W1   = (const float*)d_in[5];
  const float* b1   = (const float*)d_in[6];
  const float* W2   = (const float*)d_in[7];
  const float* b2   = (const float*)d_in[8];
  float* out = (float*)d_out;
  char* base = (char*)d_ws;

  __half* Tx       = (__half*)(base);                       // 16 KB
  __half* Ty       = (__half*)(base + 16384);               // 16 KB
  _Float16* Wt     = (_Float16*)(base + 32768);             // 1.5 MB
  _Float16* Wot    = (_Float16*)(base + 1605632);           // 512 KB
  _Float16* q16    = (_Float16*)(base + 2129920);           // 1 MB
  _Float16* k16    = (_Float16*)(base + 3178496);           // 1 MB
  _Float16* vt16   = (_Float16*)(base + 4227072);           // 1 MB
  _Float16* bias16 = (_Float16*)(base + 5275648);           // 8 MB
  _Float16* ao16   = (_Float16*)(base + 13664256);          // 1 MB

  hipLaunchKernelGGL(k_prep, dim3(1088), dim3(256), 0, stream,
                     Wqkv, Wout, W1, b1, Wt, Wot, Tx, Ty);
  hipLaunchKernelGGL(k_fused, dim3(1216), dim3(512), 0, stream,
                     x, Wt, q16, k16, vt16, pos, Tx, Ty, W2, b2, bias16);
  hipLaunchKernelGGL(k_attn, dim3(512), dim3(512), 0, stream,
                     q16, k16, vt16, bias16, ao16);
  hipLaunchKernelGGL(k_out, dim3(256), dim3(256), 0, stream,
                     ao16, Wot, bout, out);
}